// Round 10
// baseline (318.119 us; speedup 1.0000x reference)
//
#include <hip/hip_runtime.h>
#include <hip/hip_bf16.h>

typedef __attribute__((ext_vector_type(8))) __bf16 bf16x8;
typedef __attribute__((ext_vector_type(4))) __bf16 bf16x4;
typedef __attribute__((ext_vector_type(4))) float f32x4;
typedef __attribute__((ext_vector_type(16))) float f32x16;

#define T_TOK 2048
#define NH 32
#define NKV 4
#define HD 128
#define HID 2048
#define QKV_N 5120   // (32 + 2*4) * 128
#define QSZ 4096     // 32*128
#define KOFF 4096
#define VOFF 4608
#define ATT_N 4096

#define GLOAD_LDS16(g, l)                                              \
  __builtin_amdgcn_global_load_lds(                                    \
      (const __attribute__((address_space(1))) void*)(g),              \
      (__attribute__((address_space(3))) void*)(l), 16, 0, 0)

// ---------------- cast fp32 -> bf16 (row-major, vectorized) ----------------
__global__ __launch_bounds__(256) void cast_f32_bf16(const float* __restrict__ in,
                                                     __bf16* __restrict__ out, int n4) {
  int i = blockIdx.x * 256 + threadIdx.x;
  if (i < n4) {
    float4 v = reinterpret_cast<const float4*>(in)[i];
    bf16x4 o;
    o[0] = (__bf16)v.x; o[1] = (__bf16)v.y; o[2] = (__bf16)v.z; o[3] = (__bf16)v.w;
    reinterpret_cast<bf16x4*>(out)[i] = o;
  }
}

// ------------- cast + transpose: in fp32 [R][C] -> out bf16 [C][R] ---------
__global__ __launch_bounds__(256) void transpose_cast(const float* __restrict__ in,
                                                      __bf16* __restrict__ out,
                                                      int R, int C) {
  __shared__ __attribute__((aligned(16))) __bf16 tile[64][72];  // [c][r]
  const int c0 = blockIdx.x * 64;
  const int r0 = blockIdx.y * 64;
  const int ca = (threadIdx.x & 15) * 4;
  const int ra = (threadIdx.x >> 4) * 4;
  float4 v[4];
#pragma unroll
  for (int i = 0; i < 4; ++i)
    v[i] = *reinterpret_cast<const float4*>(&in[(size_t)(r0 + ra + i) * C + c0 + ca]);
#pragma unroll
  for (int j = 0; j < 4; ++j) {
    bf16x4 o;
#pragma unroll
    for (int i = 0; i < 4; ++i) o[i] = (__bf16)(((const float*)&v[i])[j]);
    *reinterpret_cast<bf16x4*>(&tile[ca + j][ra]) = o;
  }
  __syncthreads();
#pragma unroll
  for (int i = 0; i < 2; ++i) {
    int c = i * 32 + (threadIdx.x >> 3);
    int r8 = (threadIdx.x & 7) * 8;
    bf16x8 o = *reinterpret_cast<const bf16x8*>(&tile[c][r8]);
    *reinterpret_cast<bf16x8*>(&out[(size_t)(c0 + c) * R + r0 + r8]) = o;
  }
}

// ---- transpose V section of qkv: [t][kvh*128+d] -> vt[kvh][d][t] (bf16) ----
__global__ __launch_bounds__(256) void v_transpose(const __bf16* __restrict__ qkv,
                                                   __bf16* __restrict__ vt) {
  __shared__ __bf16 tile[64][72];
  int t0 = blockIdx.x * 64;
  int d0 = blockIdx.y * 64;
  int kvh = blockIdx.z;
  int tx = threadIdx.x & 63;
  int ty = threadIdx.x >> 6;
#pragma unroll
  for (int i = 0; i < 64; i += 4)
    tile[ty + i][tx] = qkv[(size_t)(t0 + ty + i) * QKV_N + VOFF + kvh * HD + d0 + tx];
  __syncthreads();
#pragma unroll
  for (int i = 0; i < 64; i += 4)
    vt[((size_t)kvh * HD + d0 + ty + i) * T_TOK + t0 + tx] = tile[tx][ty + i];
}

// ====== GEMM v9 (unchanged from R9): C = A*B^T, optional split-K ===========
template <int OUTF32>
__global__ __launch_bounds__(256) void gemm_v9(const __bf16* __restrict__ A,
                                               const __bf16* __restrict__ B,
                                               void* __restrict__ Cp,
                                               int M, int N, int Ktot, int KS,
                                               int nby, int nks) {
  __shared__ __attribute__((aligned(16))) __bf16 As[3][128][32];
  __shared__ __attribute__((aligned(16))) __bf16 Bs[3][128][32];
  const int tid = threadIdx.x;
  const int lane = tid & 63;
  const int wave = tid >> 6;
  const int la = lane & 15;
  const int lb = lane >> 4;
  const int wr = (wave >> 1) * 64;
  const int wc = (wave & 1) * 64;

  const int nwg = gridDim.x;
  const int cpx = nwg >> 3;
  const int swz = ((int)blockIdx.x & 7) * cpx + ((int)blockIdx.x >> 3);
  const int ks = swz % nks;
  const int t2 = swz / nks;
  const int by = t2 % nby;        // M-tile fastest -> B panel L2-hot
  const int bx = t2 / nby;
  const int rowA0 = by * 128;
  const int rowB0 = bx * 128;
  const int k00 = ks * KS;

  const int srow = wave * 16 + (lane >> 2);
  const int scol = (((lane & 3) * 16) ^ (((lane >> 2) & 3) << 4)) >> 1;  // elems
  const __bf16* Asrc0 = &A[(size_t)(rowA0 + srow) * Ktot + k00 + scol];
  const __bf16* Asrc1 = &A[(size_t)(rowA0 + 64 + srow) * Ktot + k00 + scol];
  const __bf16* Bsrc0 = &B[(size_t)(rowB0 + srow) * Ktot + k00 + scol];
  const __bf16* Bsrc1 = &B[(size_t)(rowB0 + 64 + srow) * Ktot + k00 + scol];

#define STAGEG(b, k0)                                            \
  do {                                                           \
    GLOAD_LDS16(Asrc0 + (k0), &As[b][wave * 16][0]);             \
    GLOAD_LDS16(Asrc1 + (k0), &As[b][64 + wave * 16][0]);        \
    GLOAD_LDS16(Bsrc0 + (k0), &Bs[b][wave * 16][0]);             \
    GLOAD_LDS16(Bsrc1 + (k0), &Bs[b][64 + wave * 16][0]);        \
  } while (0)

  f32x4 acc[4][4] = {};

  const int nt = KS >> 5;
  STAGEG(0, 0);
  STAGEG(1, 32);
  asm volatile("s_waitcnt vmcnt(4)" ::: "memory");
  __builtin_amdgcn_s_barrier();
  __builtin_amdgcn_sched_barrier(0);

  const int rdswz = (lb * 16) ^ ((la & 3) << 4);

  int cur = 0, stg = 2;
  for (int t = 0; t < nt; ++t) {
    if (t + 2 < nt) {
      STAGEG(stg, (t + 2) * 32);
    }

    const char* Ab = (const char*)&As[cur][0][0];
    const char* Bb = (const char*)&Bs[cur][0][0];
    bf16x8 af[4], bfr[4];
#pragma unroll
    for (int m = 0; m < 4; ++m)
      af[m] = *reinterpret_cast<const bf16x8*>(Ab + (wr + m * 16 + la) * 64 + rdswz);
#pragma unroll
    for (int n = 0; n < 4; ++n)
      bfr[n] = *reinterpret_cast<const bf16x8*>(Bb + (wc + n * 16 + la) * 64 + rdswz);
    __builtin_amdgcn_s_setprio(1);
#pragma unroll
    for (int m = 0; m < 4; ++m)
#pragma unroll
      for (int n = 0; n < 4; ++n)
        acc[m][n] = __builtin_amdgcn_mfma_f32_16x16x32_bf16(af[m], bfr[n], acc[m][n], 0, 0, 0);
    __builtin_amdgcn_s_setprio(0);

    const int rem = nt - 1 - t;
    if (rem >= 2) {
      asm volatile("s_waitcnt vmcnt(4)" ::: "memory");
    } else if (rem == 1) {
      asm volatile("s_waitcnt vmcnt(0)" ::: "memory");
    }
    if (rem) {
      __builtin_amdgcn_sched_barrier(0);
      __builtin_amdgcn_s_barrier();
      __builtin_amdgcn_sched_barrier(0);
    }
    cur = (cur == 2) ? 0 : cur + 1;
    stg = (stg == 2) ? 0 : stg + 1;
  }
#undef STAGEG

#pragma unroll
  for (int m = 0; m < 4; ++m) {
#pragma unroll
    for (int n = 0; n < 4; ++n) {
#pragma unroll
      for (int r = 0; r < 4; ++r) {
        int row = rowA0 + wr + m * 16 + lb * 4 + r;
        int col = rowB0 + wc + n * 16 + la;
        if (OUTF32) {
          float* pp = (float*)Cp + (size_t)ks * M * N;
          pp[(size_t)row * N + col] = acc[m][n][r];
        } else {
          reinterpret_cast<__bf16*>(Cp)[(size_t)row * N + col] = (__bf16)acc[m][n][r];
        }
      }
    }
  }
}

// -------- split-K reduce: out[i] = p0[i] + p1[i] (fp32, vectorized) --------
__global__ __launch_bounds__(256) void reduce2_f32(const float* __restrict__ pp,
                                                   float* __restrict__ out, int n4) {
  int i = blockIdx.x * 256 + threadIdx.x;
  if (i < n4) {
    float4 a = reinterpret_cast<const float4*>(pp)[i];
    float4 b = reinterpret_cast<const float4*>(pp + (size_t)HID * T_TOK)[i];
    float4 o;
    o.x = a.x + b.x; o.y = a.y + b.y; o.z = a.z + b.z; o.w = a.w + b.w;
    reinterpret_cast<float4*>(out)[i] = o;
  }
}

// ---------------- RoPE cos/sin table: tab[t][0..63]=cos, [64..127]=sin -----
__global__ __launch_bounds__(64) void rope_table(const int* __restrict__ positions,
                                                 float* __restrict__ tab) {
  const int t = blockIdx.x;
  const int d = threadIdx.x;
  float freq = exp2f(-(float)d * 0.20762050593046015f);
  float fr = (float)positions[t] * freq;
  float c, s;
  sincosf(fr, &s, &c);
  tab[t * 128 + d] = c;
  tab[t * 128 + 64 + d] = s;
}

// ------------- RMSNorm + RoPE in-place on q/k rows of qkv buffer -----------
__global__ __launch_bounds__(128) void norm_rope(__bf16* __restrict__ qkv,
                                                 const float* __restrict__ tab,
                                                 const float* __restrict__ qw,
                                                 const float* __restrict__ kw) {
  const int t = blockIdx.x;
  const int head = blockIdx.y;
  const bool is_q = head < NH;
  const int col = is_q ? head * HD : KOFF + (head - NH) * HD;
  __bf16* row = qkv + (size_t)t * QKV_N + col;
  const int d = threadIdx.x;
  float x = (float)row[d];
  float ss = x * x;
#pragma unroll
  for (int mm = 1; mm < 64; mm <<= 1) ss += __shfl_xor(ss, mm);
  __shared__ float red[2];
  __shared__ float yl[128];
  if ((d & 63) == 0) red[d >> 6] = ss;
  __syncthreads();
  float var = (red[0] + red[1]) * (1.0f / 128.0f);
  float sc = rsqrtf(var + 1e-6f);
  const float* wv = is_q ? qw : kw;
  yl[d] = x * sc * wv[d];
  __syncthreads();
  if (d < 64) {
    float x1 = yl[d], x2 = yl[d + 64];
    float c = tab[t * 128 + d];
    float sn = tab[t * 128 + 64 + d];
    row[d] = (__bf16)(x1 * c - x2 * sn);
    row[d + 64] = (__bf16)(x2 * c + x1 * sn);
  }
}

// ===== flash attention v6: 8 waves = 4 heads x 2 KV-halves ==================
// Waves 0-3 (half0): KV 32-tiles [0, mid) -- all full (no masking, proven).
// Waves 4-7 (half1): tiles [mid, nt) incl. diagonal. In-block merge via LDS.
// KVB=32, per-half dbuf gload_lds staging; LDS exactly 64KB; 2 blocks/CU =
// 4 waves/SIMD (half0+half1 waves share a SIMD -> VALU/MFMA overlap).
__device__ __forceinline__ uint32_t pkbf(float a, float b) {
  union { __bf16 h; unsigned short u; } x, y;
  x.h = (__bf16)a;
  y.h = (__bf16)b;
  return (uint32_t)x.u | ((uint32_t)y.u << 16);
}

__global__ __launch_bounds__(512, 4) void flash_attn6(const __bf16* __restrict__ qkv,
                                                      const __bf16* __restrict__ vt,
                                                      __bf16* __restrict__ attn) {
  __shared__ __attribute__((aligned(16))) char ldsB[65536];

  const int tid = threadIdx.x;
  const int lane = tid & 63;
  const int wave = tid >> 6;     // 0..7
  const int half = wave >> 2;
  const int wh = wave & 3;
  const int q5 = lane & 31;
  const int hi = lane >> 5;
  const int xx = blockIdx.x;     // 0..7
  const int kvh = xx >> 1;
  const int h = kvh * 8 + (xx & 1) * 4 + wh;
  const __bf16* Kbase = qkv + KOFF + kvh * HD;
  const __bf16* Vbase = vt + (size_t)kvh * HD * T_TOK;

  const int qt = 63 - (int)blockIdx.y;   // big blocks first
  const int qb = qt * 32;
  const int qrow = qb + q5;
  const int nt = qt + 1;                 // KV 32-tiles
  const int mid = nt >> 1;
  const int iters = nt - mid;            // >= mid, >= 1
  const int tbase = half ? mid : 0;
  const int mycnt = half ? iters : mid;

  const float qscale = 0.088388347648318447f * 1.4426950408889634f;  // rsqrt(D)*log2e

  // Q fragments (B-operand): lane holds Q[qb+q5][k0*16 + hi*8 .. +8]
  bf16x8 qf[8];
  {
    const __bf16* Qp = qkv + (size_t)(qb + q5) * QKV_N + h * HD + hi * 8;
#pragma unroll
    for (int k0 = 0; k0 < 8; ++k0) {
      bf16x8 q = *reinterpret_cast<const bf16x8*>(Qp + k0 * 16);
#pragma unroll
      for (int j = 0; j < 8; ++j) q[j] = (__bf16)((float)q[j] * qscale);
      qf[k0] = q;
    }
  }

  // staging geometry: per half-tile K[32][256B] (8KB) + V^T[128][64B] (8KB),
  // staged by the half's own 4 waves: wave unit u = wh*2+{0,1}, 1KB each.
  const int ku0 = wh * 2, ku1 = wh * 2 + 1;
  const int krow0 = ku0 * 4 + (lane >> 4);
  const int krow1 = ku1 * 4 + (lane >> 4);
  const int kcB = (lane & 15) * 16;
  const int ksc0 = (kcB ^ ((krow0 & 15) << 4)) >> 1;   // elems
  const int ksc1 = (kcB ^ ((krow1 & 15) << 4)) >> 1;
  const int vrow0 = ku0 * 16 + (lane >> 2);
  const int vrow1 = ku1 * 16 + (lane >> 2);
  const int vcB = (lane & 3) * 16;
  const int vsc0 = (vcB ^ ((vrow0 & 3) << 4)) >> 1;
  const int vsc1 = (vcB ^ ((vrow1 & 3) << 4)) >> 1;

#define STAGE6(b, kv00)                                                        \
  do {                                                                         \
    char* base = ldsB + ((b) * 2 + half) * 16384;                              \
    GLOAD_LDS16(Kbase + (size_t)((kv00) + krow0) * QKV_N + ksc0,               \
                base + ku0 * 1024);                                            \
    GLOAD_LDS16(Kbase + (size_t)((kv00) + krow1) * QKV_N + ksc1,               \
                base + ku1 * 1024);                                            \
    GLOAD_LDS16(Vbase + (size_t)vrow0 * T_TOK + (kv00) + vsc0,                 \
                base + 8192 + ku0 * 1024);                                     \
    GLOAD_LDS16(Vbase + (size_t)vrow1 * T_TOK + (kv00) + vsc1,                 \
                base + 8192 + ku1 * 1024);                                     \
  } while (0)

  f32x16 acc0 = {}, acc1 = {}, acc2 = {}, acc3 = {};
  float mrow = -1e30f, lrow = 0.0f;

  if (mycnt > 0) STAGE6(0, tbase * 32);

  int cur = 0;
  for (int t = 0; t < iters; ++t) {
    __builtin_amdgcn_s_barrier();
    __builtin_amdgcn_sched_barrier(0);
    if (t + 1 < mycnt) {
      STAGE6(cur ^ 1, (tbase + t + 1) * 32);
      asm volatile("s_waitcnt vmcnt(4)" ::: "memory");
    } else {
      asm volatile("s_waitcnt vmcnt(0)" ::: "memory");
    }
    __builtin_amdgcn_s_barrier();
    __builtin_amdgcn_sched_barrier(0);

    if (t < mycnt) {
      const int kv0 = (tbase + t) * 32;
      const char* Kt = ldsB + (cur * 2 + half) * 16384;
      const char* Vt = Kt + 8192;

      // ---- swapped QK^T: one 32x32 tile, log2 domain ----
      f32x16 st = {};
      __builtin_amdgcn_s_setprio(1);
#pragma unroll
      for (int k0 = 0; k0 < 8; ++k0) {
        int cS = (k0 * 32 + hi * 16) ^ ((q5 & 15) << 4);
        bf16x8 a0 = *reinterpret_cast<const bf16x8*>(Kt + q5 * 256 + cS);
        st = __builtin_amdgcn_mfma_f32_32x32x16_bf16(a0, qf[k0], st, 0, 0, 0);
      }
      __builtin_amdgcn_s_setprio(0);

      // ---- mask (diagonal tiles only; half0 never) ----
      if (kv0 + 31 > qb) {
#pragma unroll
        for (int r = 0; r < 16; ++r) {
          int kp = kv0 + (r & 3) + 8 * (r >> 2) + 4 * hi;
          if (kp > qrow) st[r] = -1e30f;
        }
      }
      // ---- in-register online softmax (defer-max THR=8) ----
      float mx = -1e30f;
#pragma unroll
      for (int r = 0; r < 16; ++r) mx = fmaxf(mx, st[r]);
      mx = fmaxf(mx, __shfl_xor(mx, 32));
      if (__any(mx > mrow + 8.0f)) {
        float mnew = fmaxf(mrow, mx);
        float corr = exp2f(mrow - mnew);
        lrow *= corr;
        acc0 *= corr; acc1 *= corr; acc2 *= corr; acc3 *= corr;
        mrow = mnew;
      }
      float ps = 0.0f;
#pragma unroll
      for (int r = 0; r < 16; ++r) {
        float p = exp2f(st[r] - mrow);
        ps += p;
        st[r] = p;
      }
      ps += __shfl_xor(ps, 32);
      lrow += ps;

      uint32_t W[8];
#pragma unroll
      for (int m = 0; m < 8; ++m) W[m] = pkbf(st[2 * m], st[2 * m + 1]);

      // ---- PV: acc[dt] += V^T_frag · P^T_frag ----
      const bool hib = (hi != 0);
#pragma unroll
      for (int ks = 0; ks < 2; ++ks) {
        const int j = 4 * ks;
        uint32_t keepA = hib ? W[j + 2] : W[j];
        uint32_t keepB = hib ? W[j + 3] : W[j + 1];
        uint32_t sendA = hib ? W[j] : W[j + 2];
        uint32_t sendB = hib ? W[j + 1] : W[j + 3];
        uint32_t recvA = (uint32_t)__shfl_xor((int)sendA, 32);
        uint32_t recvB = (uint32_t)__shfl_xor((int)sendB, 32);
        union { uint32_t u[4]; bf16x8 v; } fr;
        fr.u[0] = hib ? recvA : keepA;
        fr.u[1] = hib ? recvB : keepB;
        fr.u[2] = hib ? keepA : recvA;
        fr.u[3] = hib ? keepB : recvB;
        __builtin_amdgcn_s_setprio(1);
#pragma unroll
        for (int dt = 0; dt < 4; ++dt) {
          const int row = dt * 32 + q5;
          bf16x8 v = *reinterpret_cast<const bf16x8*>(
              Vt + row * 64 + ((ks * 32 + hi * 16) ^ ((row & 3) << 4)));
          if (dt == 0) acc0 = __builtin_amdgcn_mfma_f32_32x32x16_bf16(v, fr.v, acc0, 0, 0, 0);
          else if (dt == 1) acc1 = __builtin_amdgcn_mfma_f32_32x32x16_bf16(v, fr.v, acc1, 0, 0, 0);
          else if (dt == 2) acc2 = __builtin_amdgcn_mfma_f32_32x32x16_bf16(v, fr.v, acc2, 0, 0, 0);
          else acc3 = __builtin_amdgcn_mfma_f32_32x32x16_bf16(v, fr.v, acc3, 0, 0, 0);
        }
        __builtin_amdgcn_s_setprio(0);
      }
    }
    cur ^= 1;
  }
#undef STAGE6

  // ===== in-block merge of the two KV-halves =====
  __syncthreads();
  __bf16* Osh = (__bf16*)(ldsB + wh * 8192);             // [128 d][32 q] bf16
  float2* mlsh = (float2*)(ldsB + 32768);                // [4][32]
  if (half == 1) {
#pragma unroll
    for (int dt = 0; dt < 4; ++dt) {
      f32x16 a = dt == 0 ? acc0 : dt == 1 ? acc1 : dt == 2 ? acc2 : acc3;
#pragma unroll
      for (int r = 0; r < 16; ++r) {
        int row = dt * 32 + (r & 3) + 8 * (r >> 2) + 4 * hi;
        Osh[row * 32 + q5] = (__bf16)a[r];
      }
    }
    if (hi == 0) mlsh[wh * 32 + q5] = make_float2(mrow, lrow);
  }
  __syncthreads();
  if (half == 0) {
    float2 ml1 = mlsh[wh * 32 + q5];
    float m = fmaxf(mrow, ml1.x);
    float c0 = exp2f(mrow - m);
    float c1 = exp2f(ml1.x - m);
    float inv = 1.0f / (lrow * c0 + ml1.y * c1);
#pragma unroll
    for (int dt = 0; dt < 4; ++dt) {
      f32x16 a = dt == 0 ? acc0 : dt == 1 ? acc1 : dt == 2 ? acc2 : acc3;
#pragma unroll
      for (int r = 0; r < 16; ++r) {
        int row = dt * 32 + (r & 3) + 8 * (r >> 2) + 4 * hi;
        a[r] = (a[r] * c0 + (float)Osh[row * 32 + q5] * c1) * inv;
      }
      if (dt == 0) acc0 = a; else if (dt == 1) acc1 = a;
      else if (dt == 2) acc2 = a; else acc3 = a;
    }
  }
  __syncthreads();

  // ---- epilogue (half0 waves): LDS transpose, coalesced bf16x8 store ----
  if (half == 0) {
    char* ob = ldsB + wh * 8192;   // [32 q][256B], swizzled (q&15)<<4
    const int swzE = (q5 & 15) << 4;
#pragma unroll
    for (int dt = 0; dt < 4; ++dt) {
      f32x16 a = dt == 0 ? acc0 : dt == 1 ? acc1 : dt == 2 ? acc2 : acc3;
#pragma unroll
      for (int t4 = 0; t4 < 4; ++t4) {
        uint2 wv;
        wv.x = pkbf(a[4 * t4], a[4 * t4 + 1]);
        wv.y = pkbf(a[4 * t4 + 2], a[4 * t4 + 3]);
        int d2 = (dt * 32 + 8 * t4 + 4 * hi) * 2;
        *reinterpret_cast<uint2*>(ob + q5 * 256 + (d2 ^ swzE)) = wv;
      }
    }
#pragma unroll
    for (int rr = 0; rr < 8; ++rr) {
      int idx = rr * 64 + lane;
      int q = idx >> 4;
      int cc = (idx & 15) * 16;
      bf16x8 o = *reinterpret_cast<const bf16x8*>(ob + q * 256 + (cc ^ ((q & 15) << 4)));
      *reinterpret_cast<bf16x8*>(&attn[(size_t)(qb + q) * ATT_N + h * HD + (cc >> 1)]) = o;
    }
  }
}

extern "C" void kernel_launch(void* const* d_in, const int* in_sizes, int n_in,
                              void* d_out, int out_size, void* d_ws, size_t ws_size,
                              hipStream_t stream) {
  const float* hs   = (const float*)d_in[0];
  const int*   pos  = (const int*)d_in[1];
  const float* wqkv = (const float*)d_in[2];
  const float* wo   = (const float*)d_in[3];
  const float* qw   = (const float*)d_in[4];
  const float* kw   = (const float*)d_in[5];
  float* out = (float*)d_out;

  char* p = (char*)d_ws;
  __bf16* hsb   = (__bf16*)p; p += (size_t)T_TOK * HID * 2;
  __bf16* wqkvT = (__bf16*)p; p += (size_t)QKV_N * HID * 2;
  __bf16* woT   = (__bf16*)p; p += (size_t)HID * QSZ * 2;
  __bf16* qkvb  = (__bf16*)p; p += (size_t)T_TOK * QKV_N * 2;
  __bf16* attnb = (__bf16*)p; p += (size_t)T_TOK * QSZ * 2;
  __bf16* vtb   = (__bf16*)p; p += (size_t)NKV * HD * T_TOK * 2;
  float*  ropet = (float*)p;  p += (size_t)T_TOK * HD * 4;
  float*  oprt  = (float*)p;  p += (size_t)2 * T_TOK * HID * 4;  // split-K partials

  cast_f32_bf16<<<(T_TOK * HID / 4) / 256, 256, 0, stream>>>(hs, hsb, T_TOK * HID / 4);
  transpose_cast<<<dim3(QKV_N / 64, HID / 64), 256, 0, stream>>>(wqkv, wqkvT, HID, QKV_N);
  transpose_cast<<<dim3(HID / 64, QSZ / 64), 256, 0, stream>>>(wo, woT, QSZ, HID);
  rope_table<<<T_TOK, 64, 0, stream>>>(pos, ropet);
  gemm_v9<0><<<(QKV_N / 128) * (T_TOK / 128), 256, 0, stream>>>(
      hsb, wqkvT, qkvb, T_TOK, QKV_N, HID, HID, T_TOK / 128, 1);
  norm_rope<<<dim3(T_TOK, NH + NKV), 128, 0, stream>>>(qkvb, ropet, qw, kw);
  v_transpose<<<dim3(T_TOK / 64, HD / 64, NKV), 256, 0, stream>>>(qkvb, vtb);
  flash_attn6<<<dim3(8, 64), 512, 0, stream>>>(qkvb, vtb, attnb);
  gemm_v9<1><<<2 * (HID / 128) * (T_TOK / 128), 256, 0, stream>>>(
      attnb, woT, oprt, T_TOK, HID, QSZ, QSZ / 2, T_TOK / 128, 2);
  reduce2_f32<<<(T_TOK * HID / 4 + 255) / 256, 256, 0, stream>>>(
      oprt, out, T_TOK * HID / 4);
}

// Round 11
// 302.893 us; speedup vs baseline: 1.0503x; 1.0503x over previous
//
#include <hip/hip_runtime.h>
#include <hip/hip_bf16.h>

typedef __attribute__((ext_vector_type(8))) __bf16 bf16x8;
typedef __attribute__((ext_vector_type(4))) __bf16 bf16x4;
typedef __attribute__((ext_vector_type(4))) float f32x4;
typedef __attribute__((ext_vector_type(16))) float f32x16;

#define T_TOK 2048
#define NH 32
#define NKV 4
#define HD 128
#define HID 2048
#define QKV_N 5120   // (32 + 2*4) * 128
#define QSZ 4096     // 32*128
#define KOFF 4096
#define VOFF 4608
#define ATT_N 4096

#define GLOAD_LDS16(g, l)                                              \
  __builtin_amdgcn_global_load_lds(                                    \
      (const __attribute__((address_space(1))) void*)(g),              \
      (__attribute__((address_space(3))) void*)(l), 16, 0, 0)

// ---------------- cast fp32 -> bf16 (row-major, vectorized) ----------------
__global__ __launch_bounds__(256) void cast_f32_bf16(const float* __restrict__ in,
                                                     __bf16* __restrict__ out, int n4) {
  int i = blockIdx.x * 256 + threadIdx.x;
  if (i < n4) {
    float4 v = reinterpret_cast<const float4*>(in)[i];
    bf16x4 o;
    o[0] = (__bf16)v.x; o[1] = (__bf16)v.y; o[2] = (__bf16)v.z; o[3] = (__bf16)v.w;
    reinterpret_cast<bf16x4*>(out)[i] = o;
  }
}

// ------------- cast + transpose: in fp32 [R][C] -> out bf16 [C][R] ---------
__global__ __launch_bounds__(256) void transpose_cast(const float* __restrict__ in,
                                                      __bf16* __restrict__ out,
                                                      int R, int C) {
  __shared__ __attribute__((aligned(16))) __bf16 tile[64][72];  // [c][r]
  const int c0 = blockIdx.x * 64;
  const int r0 = blockIdx.y * 64;
  const int ca = (threadIdx.x & 15) * 4;
  const int ra = (threadIdx.x >> 4) * 4;
  float4 v[4];
#pragma unroll
  for (int i = 0; i < 4; ++i)
    v[i] = *reinterpret_cast<const float4*>(&in[(size_t)(r0 + ra + i) * C + c0 + ca]);
#pragma unroll
  for (int j = 0; j < 4; ++j) {
    bf16x4 o;
#pragma unroll
    for (int i = 0; i < 4; ++i) o[i] = (__bf16)(((const float*)&v[i])[j]);
    *reinterpret_cast<bf16x4*>(&tile[ca + j][ra]) = o;
  }
  __syncthreads();
#pragma unroll
  for (int i = 0; i < 2; ++i) {
    int c = i * 32 + (threadIdx.x >> 3);
    int r8 = (threadIdx.x & 7) * 8;
    bf16x8 o = *reinterpret_cast<const bf16x8*>(&tile[c][r8]);
    *reinterpret_cast<bf16x8*>(&out[(size_t)(c0 + c) * R + r0 + r8]) = o;
  }
}

// ---- transpose V section of qkv: [t][kvh*128+d] -> vt[kvh][d][t] (bf16) ----
__global__ __launch_bounds__(256) void v_transpose(const __bf16* __restrict__ qkv,
                                                   __bf16* __restrict__ vt) {
  __shared__ __bf16 tile[64][72];
  int t0 = blockIdx.x * 64;
  int d0 = blockIdx.y * 64;
  int kvh = blockIdx.z;
  int tx = threadIdx.x & 63;
  int ty = threadIdx.x >> 6;
#pragma unroll
  for (int i = 0; i < 64; i += 4)
    tile[ty + i][tx] = qkv[(size_t)(t0 + ty + i) * QKV_N + VOFF + kvh * HD + d0 + tx];
  __syncthreads();
#pragma unroll
  for (int i = 0; i < 64; i += 4)
    vt[((size_t)kvh * HD + d0 + ty + i) * T_TOK + t0 + tx] = tile[tx][ty + i];
}

// ====== GEMM v9 (unchanged from R9): C = A*B^T, optional split-K ===========
template <int OUTF32>
__global__ __launch_bounds__(256) void gemm_v9(const __bf16* __restrict__ A,
                                               const __bf16* __restrict__ B,
                                               void* __restrict__ Cp,
                                               int M, int N, int Ktot, int KS,
                                               int nby, int nks) {
  __shared__ __attribute__((aligned(16))) __bf16 As[3][128][32];
  __shared__ __attribute__((aligned(16))) __bf16 Bs[3][128][32];
  const int tid = threadIdx.x;
  const int lane = tid & 63;
  const int wave = tid >> 6;
  const int la = lane & 15;
  const int lb = lane >> 4;
  const int wr = (wave >> 1) * 64;
  const int wc = (wave & 1) * 64;

  const int nwg = gridDim.x;
  const int cpx = nwg >> 3;
  const int swz = ((int)blockIdx.x & 7) * cpx + ((int)blockIdx.x >> 3);
  const int ks = swz % nks;
  const int t2 = swz / nks;
  const int by = t2 % nby;        // M-tile fastest -> B panel L2-hot
  const int bx = t2 / nby;
  const int rowA0 = by * 128;
  const int rowB0 = bx * 128;
  const int k00 = ks * KS;

  const int srow = wave * 16 + (lane >> 2);
  const int scol = (((lane & 3) * 16) ^ (((lane >> 2) & 3) << 4)) >> 1;  // elems
  const __bf16* Asrc0 = &A[(size_t)(rowA0 + srow) * Ktot + k00 + scol];
  const __bf16* Asrc1 = &A[(size_t)(rowA0 + 64 + srow) * Ktot + k00 + scol];
  const __bf16* Bsrc0 = &B[(size_t)(rowB0 + srow) * Ktot + k00 + scol];
  const __bf16* Bsrc1 = &B[(size_t)(rowB0 + 64 + srow) * Ktot + k00 + scol];

#define STAGEG(b, k0)                                            \
  do {                                                           \
    GLOAD_LDS16(Asrc0 + (k0), &As[b][wave * 16][0]);             \
    GLOAD_LDS16(Asrc1 + (k0), &As[b][64 + wave * 16][0]);        \
    GLOAD_LDS16(Bsrc0 + (k0), &Bs[b][wave * 16][0]);             \
    GLOAD_LDS16(Bsrc1 + (k0), &Bs[b][64 + wave * 16][0]);        \
  } while (0)

  f32x4 acc[4][4] = {};

  const int nt = KS >> 5;
  STAGEG(0, 0);
  STAGEG(1, 32);
  asm volatile("s_waitcnt vmcnt(4)" ::: "memory");
  __builtin_amdgcn_s_barrier();
  __builtin_amdgcn_sched_barrier(0);

  const int rdswz = (lb * 16) ^ ((la & 3) << 4);

  int cur = 0, stg = 2;
  for (int t = 0; t < nt; ++t) {
    if (t + 2 < nt) {
      STAGEG(stg, (t + 2) * 32);
    }

    const char* Ab = (const char*)&As[cur][0][0];
    const char* Bb = (const char*)&Bs[cur][0][0];
    bf16x8 af[4], bfr[4];
#pragma unroll
    for (int m = 0; m < 4; ++m)
      af[m] = *reinterpret_cast<const bf16x8*>(Ab + (wr + m * 16 + la) * 64 + rdswz);
#pragma unroll
    for (int n = 0; n < 4; ++n)
      bfr[n] = *reinterpret_cast<const bf16x8*>(Bb + (wc + n * 16 + la) * 64 + rdswz);
    __builtin_amdgcn_s_setprio(1);
#pragma unroll
    for (int m = 0; m < 4; ++m)
#pragma unroll
      for (int n = 0; n < 4; ++n)
        acc[m][n] = __builtin_amdgcn_mfma_f32_16x16x32_bf16(af[m], bfr[n], acc[m][n], 0, 0, 0);
    __builtin_amdgcn_s_setprio(0);

    const int rem = nt - 1 - t;
    if (rem >= 2) {
      asm volatile("s_waitcnt vmcnt(4)" ::: "memory");
    } else if (rem == 1) {
      asm volatile("s_waitcnt vmcnt(0)" ::: "memory");
    }
    if (rem) {
      __builtin_amdgcn_sched_barrier(0);
      __builtin_amdgcn_s_barrier();
      __builtin_amdgcn_sched_barrier(0);
    }
    cur = (cur == 2) ? 0 : cur + 1;
    stg = (stg == 2) ? 0 : stg + 1;
  }
#undef STAGEG

#pragma unroll
  for (int m = 0; m < 4; ++m) {
#pragma unroll
    for (int n = 0; n < 4; ++n) {
#pragma unroll
      for (int r = 0; r < 4; ++r) {
        int row = rowA0 + wr + m * 16 + lb * 4 + r;
        int col = rowB0 + wc + n * 16 + la;
        if (OUTF32) {
          float* pp = (float*)Cp + (size_t)ks * M * N;
          pp[(size_t)row * N + col] = acc[m][n][r];
        } else {
          reinterpret_cast<__bf16*>(Cp)[(size_t)row * N + col] = (__bf16)acc[m][n][r];
        }
      }
    }
  }
}

// -------- split-K reduce: out[i] = p0[i] + p1[i] (fp32, vectorized) --------
__global__ __launch_bounds__(256) void reduce2_f32(const float* __restrict__ pp,
                                                   float* __restrict__ out, int n4) {
  int i = blockIdx.x * 256 + threadIdx.x;
  if (i < n4) {
    float4 a = reinterpret_cast<const float4*>(pp)[i];
    float4 b = reinterpret_cast<const float4*>(pp + (size_t)HID * T_TOK)[i];
    float4 o;
    o.x = a.x + b.x; o.y = a.y + b.y; o.z = a.z + b.z; o.w = a.w + b.w;
    reinterpret_cast<float4*>(out)[i] = o;
  }
}

// ---------------- RoPE cos/sin table: tab[t][0..63]=cos, [64..127]=sin -----
__global__ __launch_bounds__(64) void rope_table(const int* __restrict__ positions,
                                                 float* __restrict__ tab) {
  const int t = blockIdx.x;
  const int d = threadIdx.x;
  float freq = exp2f(-(float)d * 0.20762050593046015f);
  float fr = (float)positions[t] * freq;
  float c, s;
  sincosf(fr, &s, &c);
  tab[t * 128 + d] = c;
  tab[t * 128 + 64 + d] = s;
}

// ------------- RMSNorm + RoPE in-place on q/k rows of qkv buffer -----------
__global__ __launch_bounds__(128) void norm_rope(__bf16* __restrict__ qkv,
                                                 const float* __restrict__ tab,
                                                 const float* __restrict__ qw,
                                                 const float* __restrict__ kw) {
  const int t = blockIdx.x;
  const int head = blockIdx.y;
  const bool is_q = head < NH;
  const int col = is_q ? head * HD : KOFF + (head - NH) * HD;
  __bf16* row = qkv + (size_t)t * QKV_N + col;
  const int d = threadIdx.x;
  float x = (float)row[d];
  float ss = x * x;
#pragma unroll
  for (int mm = 1; mm < 64; mm <<= 1) ss += __shfl_xor(ss, mm);
  __shared__ float red[2];
  __shared__ float yl[128];
  if ((d & 63) == 0) red[d >> 6] = ss;
  __syncthreads();
  float var = (red[0] + red[1]) * (1.0f / 128.0f);
  float sc = rsqrtf(var + 1e-6f);
  const float* wv = is_q ? qw : kw;
  yl[d] = x * sc * wv[d];
  __syncthreads();
  if (d < 64) {
    float x1 = yl[d], x2 = yl[d + 64];
    float c = tab[t * 128 + d];
    float sn = tab[t * 128 + 64 + d];
    row[d] = (__bf16)(x1 * c - x2 * sn);
    row[d + 64] = (__bf16)(x2 * c + x1 * sn);
  }
}

// ===== flash attention v7: flash5 structure, 2 heads per wave ===============
// Block = 4 waves; wave w handles heads kvh*8+w and kvh*8+4+w -> every K/V
// LDS fragment read feeds TWO MFMAs (K/V frags are head-independent).
// Grid (4 kvh, 64 qtiles descending). K/V staged once per GQA group.
__device__ __forceinline__ uint32_t pkbf(float a, float b) {
  union { __bf16 h; unsigned short u; } x, y;
  x.h = (__bf16)a;
  y.h = (__bf16)b;
  return (uint32_t)x.u | ((uint32_t)y.u << 16);
}

__global__ __launch_bounds__(256, 1) void flash_attn7(const __bf16* __restrict__ qkv,
                                                      const __bf16* __restrict__ vt,
                                                      __bf16* __restrict__ attn) {
  __shared__ __attribute__((aligned(16))) __bf16 lds[32768];

  const int tid = threadIdx.x;
  const int lane = tid & 63;
  const int wave = tid >> 6;     // 0..3
  const int q5 = lane & 31;
  const int hi = lane >> 5;
  const int kvh = blockIdx.x;    // 0..3
  const int hA = kvh * 8 + wave;
  const int hB = kvh * 8 + 4 + wave;
  const __bf16* Kbase = qkv + KOFF + kvh * HD;
  const __bf16* Vbase = vt + (size_t)kvh * HD * T_TOK;

  const int qt = 63 - (int)blockIdx.y;
  const int qb = qt * 32;
  const int qrow = qb + q5;
  const int nt = (qb + 32 + 63) >> 6;

  const float qscale = 0.088388347648318447f * 1.4426950408889634f;  // rsqrt(D)*log2e

  // Q fragments for both heads
  bf16x8 qfA[8], qfB[8];
  {
    const __bf16* QpA = qkv + (size_t)(qb + q5) * QKV_N + hA * HD + hi * 8;
    const __bf16* QpB = qkv + (size_t)(qb + q5) * QKV_N + hB * HD + hi * 8;
#pragma unroll
    for (int k0 = 0; k0 < 8; ++k0) {
      bf16x8 qa = *reinterpret_cast<const bf16x8*>(QpA + k0 * 16);
      bf16x8 qb8 = *reinterpret_cast<const bf16x8*>(QpB + k0 * 16);
#pragma unroll
      for (int j = 0; j < 8; ++j) {
        qa[j] = (__bf16)((float)qa[j] * qscale);
        qb8[j] = (__bf16)((float)qb8[j] * qscale);
      }
      qfA[k0] = qa;
      qfB[k0] = qb8;
    }
  }

  const int kc = (lane & 15) * 16;
  const int vc = (lane & 7) * 16;

#define STAGE7(b, kv00)                                                         \
  do {                                                                          \
    __bf16* kdst = lds + (b) * 8192;                                            \
    __bf16* vdst = lds + 16384 + (b) * 8192;                                    \
    _Pragma("unroll")                                                           \
    for (int i = 0; i < 4; ++i) {                                               \
      int kr = wave * 16 + i * 4 + (lane >> 4);                                 \
      int ksc = (kc ^ ((kr & 15) << 4)) >> 1;                                   \
      GLOAD_LDS16(Kbase + (size_t)((kv00) + kr) * QKV_N + ksc,                  \
                  kdst + (wave * 16 + i * 4) * 128);                            \
      int vr = wave * 32 + i * 8 + (lane >> 3);                                 \
      int vsc = (vc ^ ((vr & 7) << 4)) >> 1;                                    \
      GLOAD_LDS16(Vbase + (size_t)vr * T_TOK + (kv00) + vsc,                    \
                  vdst + (wave * 32 + i * 8) * 64);                             \
    }                                                                           \
  } while (0)

  f32x16 accA0 = {}, accA1 = {}, accA2 = {}, accA3 = {};
  f32x16 accB0 = {}, accB1 = {}, accB2 = {}, accB3 = {};
  float mrowA = -1e30f, lrowA = 0.0f;
  float mrowB = -1e30f, lrowB = 0.0f;

  STAGE7(0, 0);

  int cur = 0;
  for (int t = 0; t < nt; ++t) {
    const int kv0 = t * 64;
    __builtin_amdgcn_s_barrier();
    __builtin_amdgcn_sched_barrier(0);
    if (t + 1 < nt) {
      STAGE7(cur ^ 1, kv0 + 64);
      asm volatile("s_waitcnt vmcnt(8)" ::: "memory");
    } else {
      asm volatile("s_waitcnt vmcnt(0)" ::: "memory");
    }
    __builtin_amdgcn_s_barrier();
    __builtin_amdgcn_sched_barrier(0);

    const char* Kt = (const char*)(lds + cur * 8192);
    const char* Vt = (const char*)(lds + 16384 + cur * 8192);

    // ---- swapped QK^T for BOTH heads: each K-frag read feeds 2 MFMAs ----
    f32x16 sA0 = {}, sA1 = {}, sB0 = {}, sB1 = {};
    __builtin_amdgcn_s_setprio(1);
#pragma unroll
    for (int k0 = 0; k0 < 8; ++k0) {
      int cS = (k0 * 32 + hi * 16) ^ ((q5 & 15) << 4);
      bf16x8 a0 = *reinterpret_cast<const bf16x8*>(Kt + q5 * 256 + cS);
      bf16x8 a1 = *reinterpret_cast<const bf16x8*>(Kt + (32 + q5) * 256 + cS);
      sA0 = __builtin_amdgcn_mfma_f32_32x32x16_bf16(a0, qfA[k0], sA0, 0, 0, 0);
      sB0 = __builtin_amdgcn_mfma_f32_32x32x16_bf16(a0, qfB[k0], sB0, 0, 0, 0);
      sA1 = __builtin_amdgcn_mfma_f32_32x32x16_bf16(a1, qfA[k0], sA1, 0, 0, 0);
      sB1 = __builtin_amdgcn_mfma_f32_32x32x16_bf16(a1, qfB[k0], sB1, 0, 0, 0);
    }
    __builtin_amdgcn_s_setprio(0);

    // ---- mask (diagonal tiles only; same rows for both heads) ----
    if (!(kv0 + 63 <= qb)) {
#pragma unroll
      for (int r = 0; r < 16; ++r) {
        int kp = kv0 + (r & 3) + 8 * (r >> 2) + 4 * hi;
        if (kp > qrow) { sA0[r] = -1e30f; sB0[r] = -1e30f; }
        if (kp + 32 > qrow) { sA1[r] = -1e30f; sB1[r] = -1e30f; }
      }
    }

    // ---- in-register online softmax, head A then head B ----
    float mxA = -1e30f, mxB = -1e30f;
#pragma unroll
    for (int r = 0; r < 16; ++r) {
      mxA = fmaxf(mxA, fmaxf(sA0[r], sA1[r]));
      mxB = fmaxf(mxB, fmaxf(sB0[r], sB1[r]));
    }
    mxA = fmaxf(mxA, __shfl_xor(mxA, 32));
    mxB = fmaxf(mxB, __shfl_xor(mxB, 32));
    if (__any(mxA > mrowA + 8.0f)) {
      float mnew = fmaxf(mrowA, mxA);
      float corr = exp2f(mrowA - mnew);
      lrowA *= corr;
      accA0 *= corr; accA1 *= corr; accA2 *= corr; accA3 *= corr;
      mrowA = mnew;
    }
    if (__any(mxB > mrowB + 8.0f)) {
      float mnew = fmaxf(mrowB, mxB);
      float corr = exp2f(mrowB - mnew);
      lrowB *= corr;
      accB0 *= corr; accB1 *= corr; accB2 *= corr; accB3 *= corr;
      mrowB = mnew;
    }
    float psA = 0.0f, psB = 0.0f;
#pragma unroll
    for (int r = 0; r < 16; ++r) {
      float pa0 = exp2f(sA0[r] - mrowA);
      float pa1 = exp2f(sA1[r] - mrowA);
      float pb0 = exp2f(sB0[r] - mrowB);
      float pb1 = exp2f(sB1[r] - mrowB);
      psA += pa0 + pa1;
      psB += pb0 + pb1;
      sA0[r] = pa0; sA1[r] = pa1; sB0[r] = pb0; sB1[r] = pb1;
    }
    psA += __shfl_xor(psA, 32);
    psB += __shfl_xor(psB, 32);
    lrowA += psA;
    lrowB += psB;

    // ---- pack P to bf16 words ----
    uint32_t WA0[8], WA1[8], WB0[8], WB1[8];
#pragma unroll
    for (int m = 0; m < 8; ++m) {
      WA0[m] = pkbf(sA0[2 * m], sA0[2 * m + 1]);
      WA1[m] = pkbf(sA1[2 * m], sA1[2 * m + 1]);
      WB0[m] = pkbf(sB0[2 * m], sB0[2 * m + 1]);
      WB1[m] = pkbf(sB1[2 * m], sB1[2 * m + 1]);
    }

    // ---- PV: each V-frag read feeds 2 MFMAs (heads A and B) ----
    const bool hib = (hi != 0);
#pragma unroll
    for (int ks = 0; ks < 4; ++ks) {
      const int j = 4 * (ks & 1);
      uint32_t a0, a1, a2, a3, b0, b1, b2, b3;
      if (ks < 2) {
        a0 = WA0[j]; a1 = WA0[j + 1]; a2 = WA0[j + 2]; a3 = WA0[j + 3];
        b0 = WB0[j]; b1 = WB0[j + 1]; b2 = WB0[j + 2]; b3 = WB0[j + 3];
      } else {
        a0 = WA1[j]; a1 = WA1[j + 1]; a2 = WA1[j + 2]; a3 = WA1[j + 3];
        b0 = WB1[j]; b1 = WB1[j + 1]; b2 = WB1[j + 2]; b3 = WB1[j + 3];
      }
      union { uint32_t u[4]; bf16x8 v; } frA, frB;
      {
        uint32_t keepA = hib ? a2 : a0, keepB = hib ? a3 : a1;
        uint32_t sendA = hib ? a0 : a2, sendB = hib ? a1 : a3;
        uint32_t recvA = (uint32_t)__shfl_xor((int)sendA, 32);
        uint32_t recvB = (uint32_t)__shfl_xor((int)sendB, 32);
        frA.u[0] = hib ? recvA : keepA;
        frA.u[1] = hib ? recvB : keepB;
        frA.u[2] = hib ? keepA : recvA;
        frA.u[3] = hib ? keepB : recvB;
      }
      {
        uint32_t keepA = hib ? b2 : b0, keepB = hib ? b3 : b1;
        uint32_t sendA = hib ? b0 : b2, sendB = hib ? b1 : b3;
        uint32_t recvA = (uint32_t)__shfl_xor((int)sendA, 32);
        uint32_t recvB = (uint32_t)__shfl_xor((int)sendB, 32);
        frB.u[0] = hib ? recvA : keepA;
        frB.u[1] = hib ? recvB : keepB;
        frB.u[2] = hib ? keepA : recvA;
        frB.u[3] = hib ? keepB : recvB;
      }
      const int cV = (ks * 32 + hi * 16) ^ ((q5 & 7) << 4);
      __builtin_amdgcn_s_setprio(1);
      {
        bf16x8 v0 = *reinterpret_cast<const bf16x8*>(Vt + (0 * 32 + q5) * 128 + cV);
        accA0 = __builtin_amdgcn_mfma_f32_32x32x16_bf16(v0, frA.v, accA0, 0, 0, 0);
        accB0 = __builtin_amdgcn_mfma_f32_32x32x16_bf16(v0, frB.v, accB0, 0, 0, 0);
        bf16x8 v1 = *reinterpret_cast<const bf16x8*>(Vt + (1 * 32 + q5) * 128 + cV);
        accA1 = __builtin_amdgcn_mfma_f32_32x32x16_bf16(v1, frA.v, accA1, 0, 0, 0);
        accB1 = __builtin_amdgcn_mfma_f32_32x32x16_bf16(v1, frB.v, accB1, 0, 0, 0);
        bf16x8 v2 = *reinterpret_cast<const bf16x8*>(Vt + (2 * 32 + q5) * 128 + cV);
        accA2 = __builtin_amdgcn_mfma_f32_32x32x16_bf16(v2, frA.v, accA2, 0, 0, 0);
        accB2 = __builtin_amdgcn_mfma_f32_32x32x16_bf16(v2, frB.v, accB2, 0, 0, 0);
        bf16x8 v3 = *reinterpret_cast<const bf16x8*>(Vt + (3 * 32 + q5) * 128 + cV);
        accA3 = __builtin_amdgcn_mfma_f32_32x32x16_bf16(v3, frA.v, accA3, 0, 0, 0);
        accB3 = __builtin_amdgcn_mfma_f32_32x32x16_bf16(v3, frB.v, accB3, 0, 0, 0);
      }
      __builtin_amdgcn_s_setprio(0);
    }
    cur ^= 1;
  }
#undef STAGE7

  // ---- epilogue: per-wave LDS transpose, head A then head B ----
  __syncthreads();
  {
    char* ob = (char*)lds + wave * 8192;   // [32 q][256B], swizzled (q&15)<<4
    const int swzE = (q5 & 15) << 4;
    const float invA = 1.0f / lrowA;
    const float invB = 1.0f / lrowB;
#pragma unroll
    for (int hsel = 0; hsel < 2; ++hsel) {
      const float inv = hsel ? invB : invA;
      const int h = hsel ? hB : hA;
#pragma unroll
      for (int dt = 0; dt < 4; ++dt) {
        f32x16 a;
        if (hsel == 0)
          a = dt == 0 ? accA0 : dt == 1 ? accA1 : dt == 2 ? accA2 : accA3;
        else
          a = dt == 0 ? accB0 : dt == 1 ? accB1 : dt == 2 ? accB2 : accB3;
#pragma unroll
        for (int t4 = 0; t4 < 4; ++t4) {
          uint2 wv;
          wv.x = pkbf(a[4 * t4] * inv, a[4 * t4 + 1] * inv);
          wv.y = pkbf(a[4 * t4 + 2] * inv, a[4 * t4 + 3] * inv);
          int d2 = (dt * 32 + 8 * t4 + 4 * hi) * 2;
          *reinterpret_cast<uint2*>(ob + q5 * 256 + (d2 ^ swzE)) = wv;
        }
      }
#pragma unroll
      for (int rr = 0; rr < 8; ++rr) {
        int idx = rr * 64 + lane;
        int q = idx >> 4;
        int cc = (idx & 15) * 16;
        bf16x8 o = *reinterpret_cast<const bf16x8*>(ob + q * 256 + (cc ^ ((q & 15) << 4)));
        *reinterpret_cast<bf16x8*>(&attn[(size_t)(qb + q) * ATT_N + h * HD + (cc >> 1)]) = o;
      }
    }
  }
}

extern "C" void kernel_launch(void* const* d_in, const int* in_sizes, int n_in,
                              void* d_out, int out_size, void* d_ws, size_t ws_size,
                              hipStream_t stream) {
  const float* hs   = (const float*)d_in[0];
  const int*   pos  = (const int*)d_in[1];
  const float* wqkv = (const float*)d_in[2];
  const float* wo   = (const float*)d_in[3];
  const float* qw   = (const float*)d_in[4];
  const float* kw   = (const float*)d_in[5];
  float* out = (float*)d_out;

  char* p = (char*)d_ws;
  __bf16* hsb   = (__bf16*)p; p += (size_t)T_TOK * HID * 2;
  __bf16* wqkvT = (__bf16*)p; p += (size_t)QKV_N * HID * 2;
  __bf16* woT   = (__bf16*)p; p += (size_t)HID * QSZ * 2;
  __bf16* qkvb  = (__bf16*)p; p += (size_t)T_TOK * QKV_N * 2;
  __bf16* attnb = (__bf16*)p; p += (size_t)T_TOK * QSZ * 2;
  __bf16* vtb   = (__bf16*)p; p += (size_t)NKV * HD * T_TOK * 2;
  float*  ropet = (float*)p;  p += (size_t)T_TOK * HD * 4;
  float*  oprt  = (float*)p;  p += (size_t)2 * T_TOK * HID * 4;  // split-K partials

  cast_f32_bf16<<<(T_TOK * HID / 4) / 256, 256, 0, stream>>>(hs, hsb, T_TOK * HID / 4);
  transpose_cast<<<dim3(QKV_N / 64, HID / 64), 256, 0, stream>>>(wqkv, wqkvT, HID, QKV_N);
  transpose_cast<<<dim3(HID / 64, QSZ / 64), 256, 0, stream>>>(wo, woT, QSZ, HID);
  rope_table<<<T_TOK, 64, 0, stream>>>(pos, ropet);
  gemm_v9<0><<<(QKV_N / 128) * (T_TOK / 128), 256, 0, stream>>>(
      hsb, wqkvT, qkvb, T_TOK, QKV_N, HID, HID, T_TOK / 128, 1);
  norm_rope<<<dim3(T_TOK, NH + NKV), 128, 0, stream>>>(qkvb, ropet, qw, kw);
  v_transpose<<<dim3(T_TOK / 64, HD / 64, NKV), 256, 0, stream>>>(qkvb, vtb);
  flash_attn7<<<dim3(NKV, 64), 256, 0, stream>>>(qkvb, vtb, attnb);
  gemm_v9<1><<<2 * (HID / 128) * (T_TOK / 128), 256, 0, stream>>>(
      attnb, woT, oprt, T_TOK, HID, QSZ, QSZ / 2, T_TOK / 128, 2);
  reduce2_f32<<<(T_TOK * HID / 4 + 255) / 256, 256, 0, stream>>>(
      oprt, out, T_TOK * HID / 4);
}

// Round 12
// 235.496 us; speedup vs baseline: 1.3508x; 1.2862x over previous
//
#include <hip/hip_runtime.h>
#include <hip/hip_bf16.h>

typedef __attribute__((ext_vector_type(8))) __bf16 bf16x8;
typedef __attribute__((ext_vector_type(4))) __bf16 bf16x4;
typedef __attribute__((ext_vector_type(2))) __bf16 bf16x2;
typedef __attribute__((ext_vector_type(4))) float f32x4;
typedef __attribute__((ext_vector_type(16))) float f32x16;

#define T_TOK 2048
#define NH 32
#define NKV 4
#define HD 128
#define HID 2048
#define QKV_N 5120   // (32 + 2*4) * 128
#define QSZ 4096     // 32*128
#define KOFF 4096
#define VOFF 4608
#define ATT_N 4096

#define GLOAD_LDS16(g, l)                                              \
  __builtin_amdgcn_global_load_lds(                                    \
      (const __attribute__((address_space(1))) void*)(g),              \
      (__attribute__((address_space(3))) void*)(l), 16, 0, 0)

// ---------------- cast fp32 -> bf16 (row-major, vectorized) ----------------
__global__ __launch_bounds__(256) void cast_f32_bf16(const float* __restrict__ in,
                                                     __bf16* __restrict__ out, int n4) {
  int i = blockIdx.x * 256 + threadIdx.x;
  if (i < n4) {
    float4 v = reinterpret_cast<const float4*>(in)[i];
    bf16x4 o;
    o[0] = (__bf16)v.x; o[1] = (__bf16)v.y; o[2] = (__bf16)v.z; o[3] = (__bf16)v.w;
    reinterpret_cast<bf16x4*>(out)[i] = o;
  }
}

// ------------- cast + transpose: in fp32 [R][C] -> out bf16 [C][R] ---------
__global__ __launch_bounds__(256) void transpose_cast(const float* __restrict__ in,
                                                      __bf16* __restrict__ out,
                                                      int R, int C) {
  __shared__ __attribute__((aligned(16))) __bf16 tile[64][72];  // [c][r]
  const int c0 = blockIdx.x * 64;
  const int r0 = blockIdx.y * 64;
  const int ca = (threadIdx.x & 15) * 4;
  const int ra = (threadIdx.x >> 4) * 4;
  float4 v[4];
#pragma unroll
  for (int i = 0; i < 4; ++i)
    v[i] = *reinterpret_cast<const float4*>(&in[(size_t)(r0 + ra + i) * C + c0 + ca]);
#pragma unroll
  for (int j = 0; j < 4; ++j) {
    bf16x4 o;
#pragma unroll
    for (int i = 0; i < 4; ++i) o[i] = (__bf16)(((const float*)&v[i])[j]);
    *reinterpret_cast<bf16x4*>(&tile[ca + j][ra]) = o;
  }
  __syncthreads();
#pragma unroll
  for (int i = 0; i < 2; ++i) {
    int c = i * 32 + (threadIdx.x >> 3);
    int r8 = (threadIdx.x & 7) * 8;
    bf16x8 o = *reinterpret_cast<const bf16x8*>(&tile[c][r8]);
    *reinterpret_cast<bf16x8*>(&out[(size_t)(c0 + c) * R + r0 + r8]) = o;
  }
}

// ---- transpose V section of qkv: [t][kvh*128+d] -> vt[kvh][d][t] (bf16) ----
__global__ __launch_bounds__(256) void v_transpose(const __bf16* __restrict__ qkv,
                                                   __bf16* __restrict__ vt) {
  __shared__ __bf16 tile[64][72];
  int t0 = blockIdx.x * 64;
  int d0 = blockIdx.y * 64;
  int kvh = blockIdx.z;
  int tx = threadIdx.x & 63;
  int ty = threadIdx.x >> 6;
#pragma unroll
  for (int i = 0; i < 64; i += 4)
    tile[ty + i][tx] = qkv[(size_t)(t0 + ty + i) * QKV_N + VOFF + kvh * HD + d0 + tx];
  __syncthreads();
#pragma unroll
  for (int i = 0; i < 64; i += 4)
    vt[((size_t)kvh * HD + d0 + ty + i) * T_TOK + t0 + tx] = tile[tx][ty + i];
}

// ====== GEMM v9: C = A*B^T; MODE 0 = bf16 C, MODE 1 = bf16 split-K partials =
template <int MODE>
__global__ __launch_bounds__(256) void gemm_v9(const __bf16* __restrict__ A,
                                               const __bf16* __restrict__ B,
                                               void* __restrict__ Cp,
                                               int M, int N, int Ktot, int KS,
                                               int nby, int nks) {
  __shared__ __attribute__((aligned(16))) __bf16 As[3][128][32];
  __shared__ __attribute__((aligned(16))) __bf16 Bs[3][128][32];
  const int tid = threadIdx.x;
  const int lane = tid & 63;
  const int wave = tid >> 6;
  const int la = lane & 15;
  const int lb = lane >> 4;
  const int wr = (wave >> 1) * 64;
  const int wc = (wave & 1) * 64;

  const int nwg = gridDim.x;
  const int cpx = nwg >> 3;
  const int swz = ((int)blockIdx.x & 7) * cpx + ((int)blockIdx.x >> 3);
  const int ks = swz % nks;
  const int t2 = swz / nks;
  const int by = t2 % nby;        // M-tile fastest -> B panel L2-hot
  const int bx = t2 / nby;
  const int rowA0 = by * 128;
  const int rowB0 = bx * 128;
  const int k00 = ks * KS;

  const int srow = wave * 16 + (lane >> 2);
  const int scol = (((lane & 3) * 16) ^ (((lane >> 2) & 3) << 4)) >> 1;  // elems
  const __bf16* Asrc0 = &A[(size_t)(rowA0 + srow) * Ktot + k00 + scol];
  const __bf16* Asrc1 = &A[(size_t)(rowA0 + 64 + srow) * Ktot + k00 + scol];
  const __bf16* Bsrc0 = &B[(size_t)(rowB0 + srow) * Ktot + k00 + scol];
  const __bf16* Bsrc1 = &B[(size_t)(rowB0 + 64 + srow) * Ktot + k00 + scol];

#define STAGEG(b, k0)                                            \
  do {                                                           \
    GLOAD_LDS16(Asrc0 + (k0), &As[b][wave * 16][0]);             \
    GLOAD_LDS16(Asrc1 + (k0), &As[b][64 + wave * 16][0]);        \
    GLOAD_LDS16(Bsrc0 + (k0), &Bs[b][wave * 16][0]);             \
    GLOAD_LDS16(Bsrc1 + (k0), &Bs[b][64 + wave * 16][0]);        \
  } while (0)

  f32x4 acc[4][4] = {};

  const int nt = KS >> 5;
  STAGEG(0, 0);
  STAGEG(1, 32);
  asm volatile("s_waitcnt vmcnt(4)" ::: "memory");
  __builtin_amdgcn_s_barrier();
  __builtin_amdgcn_sched_barrier(0);

  const int rdswz = (lb * 16) ^ ((la & 3) << 4);

  int cur = 0, stg = 2;
  for (int t = 0; t < nt; ++t) {
    if (t + 2 < nt) {
      STAGEG(stg, (t + 2) * 32);
    }

    const char* Ab = (const char*)&As[cur][0][0];
    const char* Bb = (const char*)&Bs[cur][0][0];
    bf16x8 af[4], bfr[4];
#pragma unroll
    for (int m = 0; m < 4; ++m)
      af[m] = *reinterpret_cast<const bf16x8*>(Ab + (wr + m * 16 + la) * 64 + rdswz);
#pragma unroll
    for (int n = 0; n < 4; ++n)
      bfr[n] = *reinterpret_cast<const bf16x8*>(Bb + (wc + n * 16 + la) * 64 + rdswz);
    __builtin_amdgcn_s_setprio(1);
#pragma unroll
    for (int m = 0; m < 4; ++m)
#pragma unroll
      for (int n = 0; n < 4; ++n)
        acc[m][n] = __builtin_amdgcn_mfma_f32_16x16x32_bf16(af[m], bfr[n], acc[m][n], 0, 0, 0);
    __builtin_amdgcn_s_setprio(0);

    const int rem = nt - 1 - t;
    if (rem >= 2) {
      asm volatile("s_waitcnt vmcnt(4)" ::: "memory");
    } else if (rem == 1) {
      asm volatile("s_waitcnt vmcnt(0)" ::: "memory");
    }
    if (rem) {
      __builtin_amdgcn_sched_barrier(0);
      __builtin_amdgcn_s_barrier();
      __builtin_amdgcn_sched_barrier(0);
    }
    cur = (cur == 2) ? 0 : cur + 1;
    stg = (stg == 2) ? 0 : stg + 1;
  }
#undef STAGEG

#pragma unroll
  for (int m = 0; m < 4; ++m) {
#pragma unroll
    for (int n = 0; n < 4; ++n) {
#pragma unroll
      for (int r = 0; r < 4; ++r) {
        int row = rowA0 + wr + m * 16 + lb * 4 + r;
        int col = rowB0 + wc + n * 16 + la;
        if (MODE == 1) {
          __bf16* pp = (__bf16*)Cp + (size_t)ks * M * N;
          pp[(size_t)row * N + col] = (__bf16)acc[m][n][r];
        } else {
          reinterpret_cast<__bf16*>(Cp)[(size_t)row * N + col] = (__bf16)acc[m][n][r];
        }
      }
    }
  }
}

// ---- split-K reduce: out[i] = (f32)p0[i] + (f32)p1[i], bf16 partials ------
__global__ __launch_bounds__(256) void reduce2_bf(const __bf16* __restrict__ pp,
                                                  float* __restrict__ out, int n8) {
  int i = blockIdx.x * 256 + threadIdx.x;
  if (i < n8) {
    bf16x8 a = reinterpret_cast<const bf16x8*>(pp)[i];
    bf16x8 b = reinterpret_cast<const bf16x8*>(pp + (size_t)HID * T_TOK)[i];
    float4 o0, o1;
    o0.x = (float)a[0] + (float)b[0];
    o0.y = (float)a[1] + (float)b[1];
    o0.z = (float)a[2] + (float)b[2];
    o0.w = (float)a[3] + (float)b[3];
    o1.x = (float)a[4] + (float)b[4];
    o1.y = (float)a[5] + (float)b[5];
    o1.z = (float)a[6] + (float)b[6];
    o1.w = (float)a[7] + (float)b[7];
    reinterpret_cast<float4*>(out)[2 * i] = o0;
    reinterpret_cast<float4*>(out)[2 * i + 1] = o1;
  }
}

// ---------------- RoPE cos/sin table: tab[t][0..63]=cos, [64..127]=sin -----
__global__ __launch_bounds__(64) void rope_table(const int* __restrict__ positions,
                                                 float* __restrict__ tab) {
  const int t = blockIdx.x;
  const int d = threadIdx.x;
  float freq = exp2f(-(float)d * 0.20762050593046015f);
  float fr = (float)positions[t] * freq;
  float c, s;
  sincosf(fr, &s, &c);
  tab[t * 128 + d] = c;
  tab[t * 128 + 64 + d] = s;
}

// ----- RMSNorm + RoPE, wave-per-row: bf16x2 loads, shuffle-only, no LDS ----
// grid (T, 9), 256 threads = 4 waves; wave w handles head blockIdx.y*4+w.
__global__ __launch_bounds__(256) void norm_rope_w(__bf16* __restrict__ qkv,
                                                   const float* __restrict__ tab,
                                                   const float* __restrict__ qw,
                                                   const float* __restrict__ kw) {
  const int t = blockIdx.x;
  const int wave = threadIdx.x >> 6;
  const int lane = threadIdx.x & 63;
  const int head = blockIdx.y * 4 + wave;  // 0..35
  const bool is_q = head < NH;
  const int col = is_q ? head * HD : KOFF + (head - NH) * HD;
  __bf16* row = qkv + (size_t)t * QKV_N + col;

  bf16x2 v = *reinterpret_cast<const bf16x2*>(&row[lane * 2]);
  float x0 = (float)v[0], x1 = (float)v[1];
  float ss = x0 * x0 + x1 * x1;
#pragma unroll
  for (int mm = 1; mm < 64; mm <<= 1) ss += __shfl_xor(ss, mm);
  float sc = rsqrtf(ss * (1.0f / 128.0f) + 1e-6f);
  const float* wv = is_q ? qw : kw;
  float y0 = x0 * sc * wv[lane * 2];
  float y1 = x1 * sc * wv[lane * 2 + 1];
  float o0 = __shfl_xor(y0, 32);   // partner: d <-> d+64
  float o1 = __shfl_xor(y1, 32);
  const int dbase = (lane & 31) * 2;
  float c0 = tab[t * 128 + dbase], c1 = tab[t * 128 + dbase + 1];
  float s0 = tab[t * 128 + 64 + dbase], s1 = tab[t * 128 + 64 + dbase + 1];
  float r0, r1;
  if (lane < 32) { r0 = y0 * c0 - o0 * s0; r1 = y1 * c1 - o1 * s1; }
  else           { r0 = y0 * c0 + o0 * s0; r1 = y1 * c1 + o1 * s1; }
  bf16x2 ov;
  ov[0] = (__bf16)r0;
  ov[1] = (__bf16)r1;
  *reinterpret_cast<bf16x2*>(&row[lane * 2]) = ov;
}

// ===== flash attention v5 (R9-proven): swapped-QK^T 32x32, 4 waves/4 heads ==
__device__ __forceinline__ uint32_t pkbf(float a, float b) {
  union { __bf16 h; unsigned short u; } x, y;
  x.h = (__bf16)a;
  y.h = (__bf16)b;
  return (uint32_t)x.u | ((uint32_t)y.u << 16);
}

__global__ __launch_bounds__(256, 2) void flash_attn5(const __bf16* __restrict__ qkv,
                                                      const __bf16* __restrict__ vt,
                                                      __bf16* __restrict__ attn) {
  __shared__ __attribute__((aligned(16))) __bf16 lds[32768];

  const int tid = threadIdx.x;
  const int lane = tid & 63;
  const int wave = tid >> 6;     // 0..3
  const int q5 = lane & 31;
  const int hi = lane >> 5;
  const int yy = blockIdx.x;     // 0..7
  const int kvh = yy >> 1;
  const int h = kvh * 8 + (yy & 1) * 4 + wave;
  const __bf16* Kbase = qkv + KOFF + kvh * HD;
  const __bf16* Vbase = vt + (size_t)kvh * HD * T_TOK;

  const int qt = 63 - (int)blockIdx.y;
  const int qb = qt * 32;
  const int qrow = qb + q5;
  const int nt = (qb + 32 + 63) >> 6;

  const float qscale = 0.088388347648318447f * 1.4426950408889634f;

  bf16x8 qf[8];
  {
    const __bf16* Qp = qkv + (size_t)(qb + q5) * QKV_N + h * HD + hi * 8;
#pragma unroll
    for (int k0 = 0; k0 < 8; ++k0) {
      bf16x8 q = *reinterpret_cast<const bf16x8*>(Qp + k0 * 16);
#pragma unroll
      for (int j = 0; j < 8; ++j) q[j] = (__bf16)((float)q[j] * qscale);
      qf[k0] = q;
    }
  }

  const int kc = (lane & 15) * 16;
  const int vc = (lane & 7) * 16;

#define STAGE5(b, kv00)                                                         \
  do {                                                                          \
    __bf16* kdst = lds + (b) * 8192;                                            \
    __bf16* vdst = lds + 16384 + (b) * 8192;                                    \
    _Pragma("unroll")                                                           \
    for (int i = 0; i < 4; ++i) {                                               \
      int kr = wave * 16 + i * 4 + (lane >> 4);                                 \
      int ksc = (kc ^ ((kr & 15) << 4)) >> 1;                                   \
      GLOAD_LDS16(Kbase + (size_t)((kv00) + kr) * QKV_N + ksc,                  \
                  kdst + (wave * 16 + i * 4) * 128);                            \
      int vr = wave * 32 + i * 8 + (lane >> 3);                                 \
      int vsc = (vc ^ ((vr & 7) << 4)) >> 1;                                    \
      GLOAD_LDS16(Vbase + (size_t)vr * T_TOK + (kv00) + vsc,                    \
                  vdst + (wave * 32 + i * 8) * 64);                             \
    }                                                                           \
  } while (0)

  f32x16 acc0 = {}, acc1 = {}, acc2 = {}, acc3 = {};
  float mrow = -1e30f, lrow = 0.0f;

  STAGE5(0, 0);

  int cur = 0;
  for (int t = 0; t < nt; ++t) {
    const int kv0 = t * 64;
    __builtin_amdgcn_s_barrier();
    __builtin_amdgcn_sched_barrier(0);
    if (t + 1 < nt) {
      STAGE5(cur ^ 1, kv0 + 64);
      asm volatile("s_waitcnt vmcnt(8)" ::: "memory");
    } else {
      asm volatile("s_waitcnt vmcnt(0)" ::: "memory");
    }
    __builtin_amdgcn_s_barrier();
    __builtin_amdgcn_sched_barrier(0);

    const char* Kt = (const char*)(lds + cur * 8192);
    const char* Vt = (const char*)(lds + 16384 + cur * 8192);

    f32x16 st0 = {}, st1 = {};
    __builtin_amdgcn_s_setprio(1);
#pragma unroll
    for (int k0 = 0; k0 < 8; ++k0) {
      int cS = (k0 * 32 + hi * 16) ^ ((q5 & 15) << 4);
      bf16x8 a0 = *reinterpret_cast<const bf16x8*>(Kt + q5 * 256 + cS);
      bf16x8 a1 = *reinterpret_cast<const bf16x8*>(Kt + (32 + q5) * 256 + cS);
      st0 = __builtin_amdgcn_mfma_f32_32x32x16_bf16(a0, qf[k0], st0, 0, 0, 0);
      st1 = __builtin_amdgcn_mfma_f32_32x32x16_bf16(a1, qf[k0], st1, 0, 0, 0);
    }
    __builtin_amdgcn_s_setprio(0);

    if (!(kv0 + 63 <= qb)) {
#pragma unroll
      for (int r = 0; r < 16; ++r) {
        int kp = kv0 + (r & 3) + 8 * (r >> 2) + 4 * hi;
        if (kp > qrow) st0[r] = -1e30f;
        if (kp + 32 > qrow) st1[r] = -1e30f;
      }
    }
    float mx = -1e30f;
#pragma unroll
    for (int r = 0; r < 16; ++r) mx = fmaxf(mx, fmaxf(st0[r], st1[r]));
    mx = fmaxf(mx, __shfl_xor(mx, 32));
    if (__any(mx > mrow + 8.0f)) {
      float mnew = fmaxf(mrow, mx);
      float corr = exp2f(mrow - mnew);
      lrow *= corr;
      acc0 *= corr; acc1 *= corr; acc2 *= corr; acc3 *= corr;
      mrow = mnew;
    }
    float ps = 0.0f;
#pragma unroll
    for (int r = 0; r < 16; ++r) {
      float p0 = exp2f(st0[r] - mrow);
      float p1 = exp2f(st1[r] - mrow);
      ps += p0 + p1;
      st0[r] = p0;
      st1[r] = p1;
    }
    ps += __shfl_xor(ps, 32);
    lrow += ps;

    uint32_t W0[8], W1[8];
#pragma unroll
    for (int m = 0; m < 8; ++m) {
      W0[m] = pkbf(st0[2 * m], st0[2 * m + 1]);
      W1[m] = pkbf(st1[2 * m], st1[2 * m + 1]);
    }

    const bool hib = (hi != 0);
#pragma unroll
    for (int ks = 0; ks < 4; ++ks) {
      const int j = 4 * (ks & 1);
      uint32_t wj0, wj1, wj2, wj3;
      if (ks < 2) { wj0 = W0[j]; wj1 = W0[j + 1]; wj2 = W0[j + 2]; wj3 = W0[j + 3]; }
      else        { wj0 = W1[j]; wj1 = W1[j + 1]; wj2 = W1[j + 2]; wj3 = W1[j + 3]; }
      uint32_t keepA = hib ? wj2 : wj0;
      uint32_t keepB = hib ? wj3 : wj1;
      uint32_t sendA = hib ? wj0 : wj2;
      uint32_t sendB = hib ? wj1 : wj3;
      uint32_t recvA = (uint32_t)__shfl_xor((int)sendA, 32);
      uint32_t recvB = (uint32_t)__shfl_xor((int)sendB, 32);
      union { uint32_t u[4]; bf16x8 v; } fr;
      fr.u[0] = hib ? recvA : keepA;
      fr.u[1] = hib ? recvB : keepB;
      fr.u[2] = hib ? keepA : recvA;
      fr.u[3] = hib ? keepB : recvB;
      const int cV = (ks * 32 + hi * 16) ^ ((q5 & 7) << 4);
      __builtin_amdgcn_s_setprio(1);
      bf16x8 v0 = *reinterpret_cast<const bf16x8*>(Vt + (0 * 32 + q5) * 128 + cV);
      acc0 = __builtin_amdgcn_mfma_f32_32x32x16_bf16(v0, fr.v, acc0, 0, 0, 0);
      bf16x8 v1 = *reinterpret_cast<const bf16x8*>(Vt + (1 * 32 + q5) * 128 + cV);
      acc1 = __builtin_amdgcn_mfma_f32_32x32x16_bf16(v1, fr.v, acc1, 0, 0, 0);
      bf16x8 v2 = *reinterpret_cast<const bf16x8*>(Vt + (2 * 32 + q5) * 128 + cV);
      acc2 = __builtin_amdgcn_mfma_f32_32x32x16_bf16(v2, fr.v, acc2, 0, 0, 0);
      bf16x8 v3 = *reinterpret_cast<const bf16x8*>(Vt + (3 * 32 + q5) * 128 + cV);
      acc3 = __builtin_amdgcn_mfma_f32_32x32x16_bf16(v3, fr.v, acc3, 0, 0, 0);
      __builtin_amdgcn_s_setprio(0);
    }
    cur ^= 1;
  }

  __syncthreads();
  {
    char* ob = (char*)lds + wave * 8192;
    float inv = 1.0f / lrow;
    const int swzE = (q5 & 15) << 4;
#pragma unroll
    for (int dt = 0; dt < 4; ++dt) {
      f32x16 a = dt == 0 ? acc0 : dt == 1 ? acc1 : dt == 2 ? acc2 : acc3;
#pragma unroll
      for (int t4 = 0; t4 < 4; ++t4) {
        uint2 wv;
        wv.x = pkbf(a[4 * t4] * inv, a[4 * t4 + 1] * inv);
        wv.y = pkbf(a[4 * t4 + 2] * inv, a[4 * t4 + 3] * inv);
        int d2 = (dt * 32 + 8 * t4 + 4 * hi) * 2;
        *reinterpret_cast<uint2*>(ob + q5 * 256 + (d2 ^ swzE)) = wv;
      }
    }
#pragma unroll
    for (int rr = 0; rr < 8; ++rr) {
      int idx = rr * 64 + lane;
      int q = idx >> 4;
      int cc = (idx & 15) * 16;
      bf16x8 o = *reinterpret_cast<const bf16x8*>(ob + q * 256 + (cc ^ ((q & 15) << 4)));
      *reinterpret_cast<bf16x8*>(&attn[(size_t)(qb + q) * ATT_N + h * HD + (cc >> 1)]) = o;
    }
  }
}

extern "C" void kernel_launch(void* const* d_in, const int* in_sizes, int n_in,
                              void* d_out, int out_size, void* d_ws, size_t ws_size,
                              hipStream_t stream) {
  const float* hs   = (const float*)d_in[0];
  const int*   pos  = (const int*)d_in[1];
  const float* wqkv = (const float*)d_in[2];
  const float* wo   = (const float*)d_in[3];
  const float* qw   = (const float*)d_in[4];
  const float* kw   = (const float*)d_in[5];
  float* out = (float*)d_out;

  char* p = (char*)d_ws;
  __bf16* hsb   = (__bf16*)p; p += (size_t)T_TOK * HID * 2;
  __bf16* wqkvT = (__bf16*)p; p += (size_t)QKV_N * HID * 2;
  __bf16* woT   = (__bf16*)p; p += (size_t)HID * QSZ * 2;
  __bf16* qkvb  = (__bf16*)p; p += (size_t)T_TOK * QKV_N * 2;
  __bf16* attnb = (__bf16*)p; p += (size_t)T_TOK * QSZ * 2;
  __bf16* vtb   = (__bf16*)p; p += (size_t)NKV * HD * T_TOK * 2;
  float*  ropet = (float*)p;  p += (size_t)T_TOK * HD * 4;
  __bf16* oprt  = (__bf16*)p; p += (size_t)2 * T_TOK * HID * 2;  // bf16 split-K partials

  cast_f32_bf16<<<(T_TOK * HID / 4) / 256, 256, 0, stream>>>(hs, hsb, T_TOK * HID / 4);
  transpose_cast<<<dim3(QKV_N / 64, HID / 64), 256, 0, stream>>>(wqkv, wqkvT, HID, QKV_N);
  transpose_cast<<<dim3(HID / 64, QSZ / 64), 256, 0, stream>>>(wo, woT, QSZ, HID);
  rope_table<<<T_TOK, 64, 0, stream>>>(pos, ropet);
  gemm_v9<0><<<(QKV_N / 128) * (T_TOK / 128), 256, 0, stream>>>(
      hsb, wqkvT, qkvb, T_TOK, QKV_N, HID, HID, T_TOK / 128, 1);
  norm_rope_w<<<dim3(T_TOK, 9), 256, 0, stream>>>(qkvb, ropet, qw, kw);
  v_transpose<<<dim3(T_TOK / 64, HD / 64, NKV), 256, 0, stream>>>(qkvb, vtb);
  flash_attn5<<<dim3(8, 64), 256, 0, stream>>>(qkvb, vtb, attnb);
  gemm_v9<1><<<2 * (HID / 128) * (T_TOK / 128), 256, 0, stream>>>(
      attnb, woT, oprt, T_TOK, HID, QSZ, QSZ / 2, T_TOK / 128, 2);
  reduce2_bf<<<(T_TOK * HID / 8 + 255) / 256, 256, 0, stream>>>(
      oprt, out, T_TOK * HID / 8);
}

// Round 13
// 225.268 us; speedup vs baseline: 1.4122x; 1.0454x over previous
//
#include <hip/hip_runtime.h>
#include <hip/hip_bf16.h>

typedef __attribute__((ext_vector_type(8))) __bf16 bf16x8;
typedef __attribute__((ext_vector_type(4))) __bf16 bf16x4;
typedef __attribute__((ext_vector_type(2))) __bf16 bf16x2;
typedef __attribute__((ext_vector_type(4))) float f32x4;
typedef __attribute__((ext_vector_type(16))) float f32x16;

#define T_TOK 2048
#define NH 32
#define NKV 4
#define HD 128
#define HID 2048
#define QKV_N 5120   // (32 + 2*4) * 128
#define QSZ 4096     // 32*128
#define KOFF 4096
#define VOFF 4608
#define ATT_N 4096

#define GLOAD_LDS16(g, l)                                              \
  __builtin_amdgcn_global_load_lds(                                    \
      (const __attribute__((address_space(1))) void*)(g),              \
      (__attribute__((address_space(3))) void*)(l), 16, 0, 0)

// ===== fused prep: cast hs | transpose wqkv | transpose wo | rope table ====
// flat grid: [0,4096) cast, [4096,6656) wqkvT, [6656,8704) woT, [8704,9216) rope
__global__ __launch_bounds__(256) void prep(const float* __restrict__ hs,
                                            __bf16* __restrict__ hsb,
                                            const float* __restrict__ wqkv,
                                            __bf16* __restrict__ wqkvT,
                                            const float* __restrict__ wo,
                                            __bf16* __restrict__ woT,
                                            const int* __restrict__ positions,
                                            float* __restrict__ tab) {
  __shared__ __attribute__((aligned(16))) __bf16 tile[64][72];  // [c][r]
  int idx = blockIdx.x;
  if (idx < 4096) {
    // ---- cast hs fp32 -> bf16 ----
    int i = idx * 256 + threadIdx.x;
    float4 v = reinterpret_cast<const float4*>(hs)[i];
    bf16x4 o;
    o[0] = (__bf16)v.x; o[1] = (__bf16)v.y; o[2] = (__bf16)v.z; o[3] = (__bf16)v.w;
    reinterpret_cast<bf16x4*>(hsb)[i] = o;
    return;
  }
  idx -= 4096;
  if (idx >= 4608) {
    // ---- rope table: 512 blocks x 4 t ----
    int j = idx - 4608;
    int t = j * 4 + (threadIdx.x >> 6);
    int d = threadIdx.x & 63;
    float freq = exp2f(-(float)d * 0.20762050593046015f);
    float fr = (float)positions[t] * freq;
    float c, s;
    sincosf(fr, &s, &c);
    tab[t * 128 + d] = c;
    tab[t * 128 + 64 + d] = s;
    return;
  }
  // ---- transpose_cast roles ----
  const float* in;
  __bf16* out;
  int R, C, bx, by;
  if (idx < 2560) { in = wqkv; out = wqkvT; R = HID; C = QKV_N; bx = idx % 80; by = idx / 80; }
  else { int j = idx - 2560; in = wo; out = woT; R = QSZ; C = HID; bx = j % 32; by = j / 32; }
  const int c0 = bx * 64;
  const int r0 = by * 64;
  const int ca = (threadIdx.x & 15) * 4;
  const int ra = (threadIdx.x >> 4) * 4;
  float4 v[4];
#pragma unroll
  for (int i = 0; i < 4; ++i)
    v[i] = *reinterpret_cast<const float4*>(&in[(size_t)(r0 + ra + i) * C + c0 + ca]);
#pragma unroll
  for (int j = 0; j < 4; ++j) {
    bf16x4 o;
#pragma unroll
    for (int i = 0; i < 4; ++i) o[i] = (__bf16)(((const float*)&v[i])[j]);
    *reinterpret_cast<bf16x4*>(&tile[ca + j][ra]) = o;
  }
  __syncthreads();
#pragma unroll
  for (int i = 0; i < 2; ++i) {
    int c = i * 32 + (threadIdx.x >> 3);
    int r8 = (threadIdx.x & 7) * 8;
    bf16x8 o = *reinterpret_cast<const bf16x8*>(&tile[c][r8]);
    *reinterpret_cast<bf16x8*>(&out[(size_t)(c0 + c) * R + r0 + r8]) = o;
  }
}

// ====== GEMM v9: C = A*B^T; MODE 0 = bf16 C, MODE 1 = bf16 split-K partials =
template <int MODE>
__global__ __launch_bounds__(256) void gemm_v9(const __bf16* __restrict__ A,
                                               const __bf16* __restrict__ B,
                                               void* __restrict__ Cp,
                                               int M, int N, int Ktot, int KS,
                                               int nby, int nks) {
  __shared__ __attribute__((aligned(16))) __bf16 As[3][128][32];
  __shared__ __attribute__((aligned(16))) __bf16 Bs[3][128][32];
  const int tid = threadIdx.x;
  const int lane = tid & 63;
  const int wave = tid >> 6;
  const int la = lane & 15;
  const int lb = lane >> 4;
  const int wr = (wave >> 1) * 64;
  const int wc = (wave & 1) * 64;

  const int nwg = gridDim.x;
  const int cpx = nwg >> 3;
  const int swz = ((int)blockIdx.x & 7) * cpx + ((int)blockIdx.x >> 3);
  const int ks = swz % nks;
  const int t2 = swz / nks;
  const int by = t2 % nby;        // M-tile fastest -> B panel L2-hot
  const int bx = t2 / nby;
  const int rowA0 = by * 128;
  const int rowB0 = bx * 128;
  const int k00 = ks * KS;

  const int srow = wave * 16 + (lane >> 2);
  const int scol = (((lane & 3) * 16) ^ (((lane >> 2) & 3) << 4)) >> 1;  // elems
  const __bf16* Asrc0 = &A[(size_t)(rowA0 + srow) * Ktot + k00 + scol];
  const __bf16* Asrc1 = &A[(size_t)(rowA0 + 64 + srow) * Ktot + k00 + scol];
  const __bf16* Bsrc0 = &B[(size_t)(rowB0 + srow) * Ktot + k00 + scol];
  const __bf16* Bsrc1 = &B[(size_t)(rowB0 + 64 + srow) * Ktot + k00 + scol];

#define STAGEG(b, k0)                                            \
  do {                                                           \
    GLOAD_LDS16(Asrc0 + (k0), &As[b][wave * 16][0]);             \
    GLOAD_LDS16(Asrc1 + (k0), &As[b][64 + wave * 16][0]);        \
    GLOAD_LDS16(Bsrc0 + (k0), &Bs[b][wave * 16][0]);             \
    GLOAD_LDS16(Bsrc1 + (k0), &Bs[b][64 + wave * 16][0]);        \
  } while (0)

  f32x4 acc[4][4] = {};

  const int nt = KS >> 5;
  STAGEG(0, 0);
  STAGEG(1, 32);
  asm volatile("s_waitcnt vmcnt(4)" ::: "memory");
  __builtin_amdgcn_s_barrier();
  __builtin_amdgcn_sched_barrier(0);

  const int rdswz = (lb * 16) ^ ((la & 3) << 4);

  int cur = 0, stg = 2;
  for (int t = 0; t < nt; ++t) {
    if (t + 2 < nt) {
      STAGEG(stg, (t + 2) * 32);
    }

    const char* Ab = (const char*)&As[cur][0][0];
    const char* Bb = (const char*)&Bs[cur][0][0];
    bf16x8 af[4], bfr[4];
#pragma unroll
    for (int m = 0; m < 4; ++m)
      af[m] = *reinterpret_cast<const bf16x8*>(Ab + (wr + m * 16 + la) * 64 + rdswz);
#pragma unroll
    for (int n = 0; n < 4; ++n)
      bfr[n] = *reinterpret_cast<const bf16x8*>(Bb + (wc + n * 16 + la) * 64 + rdswz);
    __builtin_amdgcn_s_setprio(1);
#pragma unroll
    for (int m = 0; m < 4; ++m)
#pragma unroll
      for (int n = 0; n < 4; ++n)
        acc[m][n] = __builtin_amdgcn_mfma_f32_16x16x32_bf16(af[m], bfr[n], acc[m][n], 0, 0, 0);
    __builtin_amdgcn_s_setprio(0);

    const int rem = nt - 1 - t;
    if (rem >= 2) {
      asm volatile("s_waitcnt vmcnt(4)" ::: "memory");
    } else if (rem == 1) {
      asm volatile("s_waitcnt vmcnt(0)" ::: "memory");
    }
    if (rem) {
      __builtin_amdgcn_sched_barrier(0);
      __builtin_amdgcn_s_barrier();
      __builtin_amdgcn_sched_barrier(0);
    }
    cur = (cur == 2) ? 0 : cur + 1;
    stg = (stg == 2) ? 0 : stg + 1;
  }
#undef STAGEG

#pragma unroll
  for (int m = 0; m < 4; ++m) {
#pragma unroll
    for (int n = 0; n < 4; ++n) {
#pragma unroll
      for (int r = 0; r < 4; ++r) {
        int row = rowA0 + wr + m * 16 + lb * 4 + r;
        int col = rowB0 + wc + n * 16 + la;
        if (MODE == 1) {
          __bf16* pp = (__bf16*)Cp + (size_t)ks * M * N;
          pp[(size_t)row * N + col] = (__bf16)acc[m][n][r];
        } else {
          reinterpret_cast<__bf16*>(Cp)[(size_t)row * N + col] = (__bf16)acc[m][n][r];
        }
      }
    }
  }
}

// ---- split-K reduce: out[i] = (f32)p0[i] + (f32)p1[i], bf16 partials ------
__global__ __launch_bounds__(256) void reduce2_bf(const __bf16* __restrict__ pp,
                                                  float* __restrict__ out, int n8) {
  int i = blockIdx.x * 256 + threadIdx.x;
  if (i < n8) {
    bf16x8 a = reinterpret_cast<const bf16x8*>(pp)[i];
    bf16x8 b = reinterpret_cast<const bf16x8*>(pp + (size_t)HID * T_TOK)[i];
    float4 o0, o1;
    o0.x = (float)a[0] + (float)b[0];
    o0.y = (float)a[1] + (float)b[1];
    o0.z = (float)a[2] + (float)b[2];
    o0.w = (float)a[3] + (float)b[3];
    o1.x = (float)a[4] + (float)b[4];
    o1.y = (float)a[5] + (float)b[5];
    o1.z = (float)a[6] + (float)b[6];
    o1.w = (float)a[7] + (float)b[7];
    reinterpret_cast<float4*>(out)[2 * i] = o0;
    reinterpret_cast<float4*>(out)[2 * i + 1] = o1;
  }
}

// ===== fused post-QKV: RMSNorm+RoPE (q,k) | V transpose =====================
// flat grid: [0,18432) norm (t = idx&2047, head-group = idx>>11),
//            [18432,18688) v_transpose (256 blocks).
__global__ __launch_bounds__(256) void postqkv(__bf16* __restrict__ qkv,
                                               __bf16* __restrict__ vt,
                                               const float* __restrict__ tab,
                                               const float* __restrict__ qw,
                                               const float* __restrict__ kw) {
  __shared__ __bf16 tile[64][72];
  int idx = blockIdx.x;
  if (idx < 18432) {
    // ---- RMSNorm + RoPE, wave-per-row ----
    const int t = idx & 2047;
    const int hg = idx >> 11;              // 0..8
    const int wave = threadIdx.x >> 6;
    const int lane = threadIdx.x & 63;
    const int head = hg * 4 + wave;        // 0..35
    const bool is_q = head < NH;
    const int col = is_q ? head * HD : KOFF + (head - NH) * HD;
    __bf16* row = qkv + (size_t)t * QKV_N + col;

    bf16x2 v = *reinterpret_cast<const bf16x2*>(&row[lane * 2]);
    float x0 = (float)v[0], x1 = (float)v[1];
    float ss = x0 * x0 + x1 * x1;
#pragma unroll
    for (int mm = 1; mm < 64; mm <<= 1) ss += __shfl_xor(ss, mm);
    float sc = rsqrtf(ss * (1.0f / 128.0f) + 1e-6f);
    const float* wv = is_q ? qw : kw;
    float y0 = x0 * sc * wv[lane * 2];
    float y1 = x1 * sc * wv[lane * 2 + 1];
    float o0 = __shfl_xor(y0, 32);
    float o1 = __shfl_xor(y1, 32);
    const int dbase = (lane & 31) * 2;
    float c0 = tab[t * 128 + dbase], c1 = tab[t * 128 + dbase + 1];
    float s0 = tab[t * 128 + 64 + dbase], s1 = tab[t * 128 + 64 + dbase + 1];
    float r0, r1;
    if (lane < 32) { r0 = y0 * c0 - o0 * s0; r1 = y1 * c1 - o1 * s1; }
    else           { r0 = y0 * c0 + o0 * s0; r1 = y1 * c1 + o1 * s1; }
    bf16x2 ov;
    ov[0] = (__bf16)r0;
    ov[1] = (__bf16)r1;
    *reinterpret_cast<bf16x2*>(&row[lane * 2]) = ov;
    return;
  }
  // ---- V transpose: [t][kvh*128+d] -> vt[kvh][d][t] ----
  const int j = idx - 18432;               // 0..255
  const int t0 = (j & 31) * 64;
  const int d0 = ((j >> 5) & 1) * 64;
  const int kvh = j >> 6;
  const int tx = threadIdx.x & 63;
  const int ty = threadIdx.x >> 6;
#pragma unroll
  for (int i = 0; i < 64; i += 4)
    tile[ty + i][tx] = qkv[(size_t)(t0 + ty + i) * QKV_N + VOFF + kvh * HD + d0 + tx];
  __syncthreads();
#pragma unroll
  for (int i = 0; i < 64; i += 4)
    vt[((size_t)kvh * HD + d0 + ty + i) * T_TOK + t0 + tx] = tile[tx][ty + i];
}

// ===== flash attention v5 + tree-reduced softmax chains =====================
__device__ __forceinline__ uint32_t pkbf(float a, float b) {
  union { __bf16 h; unsigned short u; } x, y;
  x.h = (__bf16)a;
  y.h = (__bf16)b;
  return (uint32_t)x.u | ((uint32_t)y.u << 16);
}

__global__ __launch_bounds__(256, 2) void flash_attn5(const __bf16* __restrict__ qkv,
                                                      const __bf16* __restrict__ vt,
                                                      __bf16* __restrict__ attn) {
  __shared__ __attribute__((aligned(16))) __bf16 lds[32768];

  const int tid = threadIdx.x;
  const int lane = tid & 63;
  const int wave = tid >> 6;     // 0..3
  const int q5 = lane & 31;
  const int hi = lane >> 5;
  const int yy = blockIdx.x;     // 0..7
  const int kvh = yy >> 1;
  const int h = kvh * 8 + (yy & 1) * 4 + wave;
  const __bf16* Kbase = qkv + KOFF + kvh * HD;
  const __bf16* Vbase = vt + (size_t)kvh * HD * T_TOK;

  const int qt = 63 - (int)blockIdx.y;
  const int qb = qt * 32;
  const int qrow = qb + q5;
  const int nt = (qb + 32 + 63) >> 6;

  const float qscale = 0.088388347648318447f * 1.4426950408889634f;

  bf16x8 qf[8];
  {
    const __bf16* Qp = qkv + (size_t)(qb + q5) * QKV_N + h * HD + hi * 8;
#pragma unroll
    for (int k0 = 0; k0 < 8; ++k0) {
      bf16x8 q = *reinterpret_cast<const bf16x8*>(Qp + k0 * 16);
#pragma unroll
      for (int j = 0; j < 8; ++j) q[j] = (__bf16)((float)q[j] * qscale);
      qf[k0] = q;
    }
  }

  const int kc = (lane & 15) * 16;
  const int vc = (lane & 7) * 16;

#define STAGE5(b, kv00)                                                         \
  do {                                                                          \
    __bf16* kdst = lds + (b) * 8192;                                            \
    __bf16* vdst = lds + 16384 + (b) * 8192;                                    \
    _Pragma("unroll")                                                           \
    for (int i = 0; i < 4; ++i) {                                               \
      int kr = wave * 16 + i * 4 + (lane >> 4);                                 \
      int ksc = (kc ^ ((kr & 15) << 4)) >> 1;                                   \
      GLOAD_LDS16(Kbase + (size_t)((kv00) + kr) * QKV_N + ksc,                  \
                  kdst + (wave * 16 + i * 4) * 128);                            \
      int vr = wave * 32 + i * 8 + (lane >> 3);                                 \
      int vsc = (vc ^ ((vr & 7) << 4)) >> 1;                                    \
      GLOAD_LDS16(Vbase + (size_t)vr * T_TOK + (kv00) + vsc,                    \
                  vdst + (wave * 32 + i * 8) * 64);                             \
    }                                                                           \
  } while (0)

  f32x16 acc0 = {}, acc1 = {}, acc2 = {}, acc3 = {};
  float mrow = -1e30f, lrow = 0.0f;

  STAGE5(0, 0);

  int cur = 0;
  for (int t = 0; t < nt; ++t) {
    const int kv0 = t * 64;
    __builtin_amdgcn_s_barrier();
    __builtin_amdgcn_sched_barrier(0);
    if (t + 1 < nt) {
      STAGE5(cur ^ 1, kv0 + 64);
      asm volatile("s_waitcnt vmcnt(8)" ::: "memory");
    } else {
      asm volatile("s_waitcnt vmcnt(0)" ::: "memory");
    }
    __builtin_amdgcn_s_barrier();
    __builtin_amdgcn_sched_barrier(0);

    const char* Kt = (const char*)(lds + cur * 8192);
    const char* Vt = (const char*)(lds + 16384 + cur * 8192);

    f32x16 st0 = {}, st1 = {};
    __builtin_amdgcn_s_setprio(1);
#pragma unroll
    for (int k0 = 0; k0 < 8; ++k0) {
      int cS = (k0 * 32 + hi * 16) ^ ((q5 & 15) << 4);
      bf16x8 a0 = *reinterpret_cast<const bf16x8*>(Kt + q5 * 256 + cS);
      bf16x8 a1 = *reinterpret_cast<const bf16x8*>(Kt + (32 + q5) * 256 + cS);
      st0 = __builtin_amdgcn_mfma_f32_32x32x16_bf16(a0, qf[k0], st0, 0, 0, 0);
      st1 = __builtin_amdgcn_mfma_f32_32x32x16_bf16(a1, qf[k0], st1, 0, 0, 0);
    }
    __builtin_amdgcn_s_setprio(0);

    if (!(kv0 + 63 <= qb)) {
#pragma unroll
      for (int r = 0; r < 16; ++r) {
        int kp = kv0 + (r & 3) + 8 * (r >> 2) + 4 * hi;
        if (kp > qrow) st0[r] = -1e30f;
        if (kp + 32 > qrow) st1[r] = -1e30f;
      }
    }
    // ---- tree-reduced max (depth 5, was 32-deep serial chain) ----
    float tm[16];
#pragma unroll
    for (int r = 0; r < 16; ++r) tm[r] = fmaxf(st0[r], st1[r]);
#pragma unroll
    for (int s = 8; s > 0; s >>= 1)
#pragma unroll
      for (int r = 0; r < s; ++r) tm[r] = fmaxf(tm[r], tm[r + s]);
    float mx = fmaxf(tm[0], __shfl_xor(tm[0], 32));
    if (__any(mx > mrow + 8.0f)) {
      float mnew = fmaxf(mrow, mx);
      float corr = exp2f(mrow - mnew);
      lrow *= corr;
      acc0 *= corr; acc1 *= corr; acc2 *= corr; acc3 *= corr;
      mrow = mnew;
    }
    // ---- exp2 + tree-reduced sum ----
    float sv[16];
#pragma unroll
    for (int r = 0; r < 16; ++r) {
      float p0 = exp2f(st0[r] - mrow);
      float p1 = exp2f(st1[r] - mrow);
      sv[r] = p0 + p1;
      st0[r] = p0;
      st1[r] = p1;
    }
#pragma unroll
    for (int s = 8; s > 0; s >>= 1)
#pragma unroll
      for (int r = 0; r < s; ++r) sv[r] += sv[r + s];
    lrow += sv[0] + __shfl_xor(sv[0], 32);

    uint32_t W0[8], W1[8];
#pragma unroll
    for (int m = 0; m < 8; ++m) {
      W0[m] = pkbf(st0[2 * m], st0[2 * m + 1]);
      W1[m] = pkbf(st1[2 * m], st1[2 * m + 1]);
    }

    const bool hib = (hi != 0);
#pragma unroll
    for (int ks = 0; ks < 4; ++ks) {
      const int j = 4 * (ks & 1);
      uint32_t wj0, wj1, wj2, wj3;
      if (ks < 2) { wj0 = W0[j]; wj1 = W0[j + 1]; wj2 = W0[j + 2]; wj3 = W0[j + 3]; }
      else        { wj0 = W1[j]; wj1 = W1[j + 1]; wj2 = W1[j + 2]; wj3 = W1[j + 3]; }
      uint32_t keepA = hib ? wj2 : wj0;
      uint32_t keepB = hib ? wj3 : wj1;
      uint32_t sendA = hib ? wj0 : wj2;
      uint32_t sendB = hib ? wj1 : wj3;
      uint32_t recvA = (uint32_t)__shfl_xor((int)sendA, 32);
      uint32_t recvB = (uint32_t)__shfl_xor((int)sendB, 32);
      union { uint32_t u[4]; bf16x8 v; } fr;
      fr.u[0] = hib ? recvA : keepA;
      fr.u[1] = hib ? recvB : keepB;
      fr.u[2] = hib ? keepA : recvA;
      fr.u[3] = hib ? keepB : recvB;
      const int cV = (ks * 32 + hi * 16) ^ ((q5 & 7) << 4);
      __builtin_amdgcn_s_setprio(1);
      bf16x8 v0 = *reinterpret_cast<const bf16x8*>(Vt + (0 * 32 + q5) * 128 + cV);
      acc0 = __builtin_amdgcn_mfma_f32_32x32x16_bf16(v0, fr.v, acc0, 0, 0, 0);
      bf16x8 v1 = *reinterpret_cast<const bf16x8*>(Vt + (1 * 32 + q5) * 128 + cV);
      acc1 = __builtin_amdgcn_mfma_f32_32x32x16_bf16(v1, fr.v, acc1, 0, 0, 0);
      bf16x8 v2 = *reinterpret_cast<const bf16x8*>(Vt + (2 * 32 + q5) * 128 + cV);
      acc2 = __builtin_amdgcn_mfma_f32_32x32x16_bf16(v2, fr.v, acc2, 0, 0, 0);
      bf16x8 v3 = *reinterpret_cast<const bf16x8*>(Vt + (3 * 32 + q5) * 128 + cV);
      acc3 = __builtin_amdgcn_mfma_f32_32x32x16_bf16(v3, fr.v, acc3, 0, 0, 0);
      __builtin_amdgcn_s_setprio(0);
    }
    cur ^= 1;
  }

  __syncthreads();
  {
    char* ob = (char*)lds + wave * 8192;
    float inv = 1.0f / lrow;
    const int swzE = (q5 & 15) << 4;
#pragma unroll
    for (int dt = 0; dt < 4; ++dt) {
      f32x16 a = dt == 0 ? acc0 : dt == 1 ? acc1 : dt == 2 ? acc2 : acc3;
#pragma unroll
      for (int t4 = 0; t4 < 4; ++t4) {
        uint2 wv;
        wv.x = pkbf(a[4 * t4] * inv, a[4 * t4 + 1] * inv);
        wv.y = pkbf(a[4 * t4 + 2] * inv, a[4 * t4 + 3] * inv);
        int d2 = (dt * 32 + 8 * t4 + 4 * hi) * 2;
        *reinterpret_cast<uint2*>(ob + q5 * 256 + (d2 ^ swzE)) = wv;
      }
    }
#pragma unroll
    for (int rr = 0; rr < 8; ++rr) {
      int idx = rr * 64 + lane;
      int q = idx >> 4;
      int cc = (idx & 15) * 16;
      bf16x8 o = *reinterpret_cast<const bf16x8*>(ob + q * 256 + (cc ^ ((q & 15) << 4)));
      *reinterpret_cast<bf16x8*>(&attn[(size_t)(qb + q) * ATT_N + h * HD + (cc >> 1)]) = o;
    }
  }
}

extern "C" void kernel_launch(void* const* d_in, const int* in_sizes, int n_in,
                              void* d_out, int out_size, void* d_ws, size_t ws_size,
                              hipStream_t stream) {
  const float* hs   = (const float*)d_in[0];
  const int*   pos  = (const int*)d_in[1];
  const float* wqkv = (const float*)d_in[2];
  const float* wo   = (const float*)d_in[3];
  const float* qw   = (const float*)d_in[4];
  const float* kw   = (const float*)d_in[5];
  float* out = (float*)d_out;

  char* p = (char*)d_ws;
  __bf16* hsb   = (__bf16*)p; p += (size_t)T_TOK * HID * 2;
  __bf16* wqkvT = (__bf16*)p; p += (size_t)QKV_N * HID * 2;
  __bf16* woT   = (__bf16*)p; p += (size_t)HID * QSZ * 2;
  __bf16* qkvb  = (__bf16*)p; p += (size_t)T_TOK * QKV_N * 2;
  __bf16* attnb = (__bf16*)p; p += (size_t)T_TOK * QSZ * 2;
  __bf16* vtb   = (__bf16*)p; p += (size_t)NKV * HD * T_TOK * 2;
  float*  ropet = (float*)p;  p += (size_t)T_TOK * HD * 4;
  __bf16* oprt  = (__bf16*)p; p += (size_t)2 * T_TOK * HID * 2;  // bf16 split-K partials

  // 1. fused prep (cast | wqkv^T | wo^T | rope table)
  prep<<<9216, 256, 0, stream>>>(hs, hsb, wqkv, wqkvT, wo, woT, pos, ropet);
  // 2. QKV projection
  gemm_v9<0><<<(QKV_N / 128) * (T_TOK / 128), 256, 0, stream>>>(
      hsb, wqkvT, qkvb, T_TOK, QKV_N, HID, HID, T_TOK / 128, 1);
  // 3. fused RMSNorm+RoPE | V transpose
  postqkv<<<18688, 256, 0, stream>>>(qkvb, vtb, ropet, qw, kw);
  // 4. causal GQA flash attention
  flash_attn5<<<dim3(8, 64), 256, 0, stream>>>(qkvb, vtb, attnb);
  // 5. O projection, split-K=2 (bf16 partials) + reduce
  gemm_v9<1><<<2 * (HID / 128) * (T_TOK / 128), 256, 0, stream>>>(
      attnb, woT, oprt, T_TOK, HID, QSZ, QSZ / 2, T_TOK / 128, 2);
  reduce2_bf<<<(T_TOK * HID / 8 + 255) / 256, 256, 0, stream>>>(
      oprt, out, T_TOK * HID / 8);
}